// Round 3
// baseline (568.944 us; speedup 1.0000x reference)
//
#include <hip/hip_runtime.h>

// ---------------------------------------------------------------------------
// MultiHeadAttention_60000693125780 — round 8
//  Work reduction via f16: fp16 has 11 mantissa bits and f16xf16 products are
//  exact in the fp32 MFMA accumulator, so:
//   - Wq/Wk stored single-f16 (rel err ~2^-12/sqrt3), X split f16 hi+lo
//     -> conv Q/K = 2 MFMA passes (was 3 bf16 passes each)
//   - K conv output single-f16, Q output f16 hi/lo
//     -> scores = 2 passes, 3 staged arrays (was 3 passes / 4 arrays)
//  conv_qkv pass-units 7 -> 5; V/PV/conv_o paths byte-identical to round 7.
//  Predicted: conv_qkv 264->~220us, total ~455-470us, absmax <= 0.0625
//  (error budget: score delta ~0.007 abs on sigma~30 scores).
//  Round-7 lessons kept: setprio on conv_qkv = NULL (keep, inert);
//  BK=64/128 drain-halving in scores/pv/conv_o kept.
// Layouts: Qh/Ql [nn][dd][t] f16 hi/lo; Kh [nn][dd][t] f16; Vt [nn][t][dd]
//  bf16; Ph [nn][q][k'] bf16; Sp padded NHWC bf16 [4][10][258][512]
// ---------------------------------------------------------------------------

typedef __attribute__((ext_vector_type(8))) short short8;
typedef __attribute__((ext_vector_type(8))) _Float16 half8;
typedef __attribute__((ext_vector_type(4))) float f32x4;
typedef __attribute__((ext_vector_type(4))) short short4v;

#define MFMA16(a, b, c) __builtin_amdgcn_mfma_f32_16x16x32_bf16((a), (b), (c), 0, 0, 0)
#define MFMA16F(a, b, c) __builtin_amdgcn_mfma_f32_16x16x32_f16((a), (b), (c), 0, 0, 0)

__device__ __forceinline__ void gl_lds16(const void* g, void* l) {
    __builtin_amdgcn_global_load_lds(
        (const __attribute__((address_space(1))) unsigned int*)g,
        (__attribute__((address_space(3))) unsigned int*)l, 16, 0, 0);
}
__device__ __forceinline__ unsigned short f2bf(float f) {
    unsigned u = __float_as_uint(f);
    return (unsigned short)((u + 0x7fffu + ((u >> 16) & 1u)) >> 16);
}
__device__ __forceinline__ float bf2f(unsigned short h) {
    return __uint_as_float(((unsigned)h) << 16);
}
__device__ __forceinline__ unsigned int pack_hl(float f) {
    unsigned short h = f2bf(f);
    unsigned short lo = f2bf(f - bf2f(h));
    return (unsigned)h | ((unsigned)lo << 16);
}
__device__ __forceinline__ unsigned short f2h(float f) {
    _Float16 h = (_Float16)f;                       // RNE
    return __builtin_bit_cast(unsigned short, h);
}
__device__ __forceinline__ float h2f(unsigned short u) {
    return (float)__builtin_bit_cast(_Float16, u);
}
__device__ __forceinline__ unsigned int pack_hl_f16(float f) {
    unsigned short h = f2h(f);
    unsigned short l = f2h(f - h2f(h));
    return (unsigned)h | ((unsigned)l << 16);
}

// ---- fused prep: [0,1536) input transpose | [1536,3584) weights | rest halo
__global__ __launch_bounds__(256) void k_prep_fused(
        const float* __restrict__ q, const float* __restrict__ k,
        const float* __restrict__ v,
        const float* __restrict__ Wq, const float* __restrict__ Wk,
        const float* __restrict__ Wv, const float* __restrict__ Wo,
        unsigned short* __restrict__ Wqh, unsigned short* __restrict__ Wkh,
        unsigned short* __restrict__ Wvh, unsigned short* __restrict__ Woh,
        unsigned short* __restrict__ Xqh, unsigned short* __restrict__ Xql,
        unsigned short* __restrict__ Xkh, unsigned short* __restrict__ Xkl,
        unsigned short* __restrict__ Xvh) {
    __shared__ __align__(16) unsigned int U[8192];
    const int b = blockIdx.x;
    const int tid = threadIdx.x;
    if (b < 1536) {
        // ---- input prep: NCHW fp32 -> padded NHWC; q/k f16 hi+lo, v bf16 ----
        const int cig = b & 15, n = (b >> 4) & 31, z = b >> 9;
        const float* X = z == 0 ? q : z == 1 ? k : v;
        unsigned short* Xh = z == 0 ? Xqh : z == 1 ? Xkh : Xvh;
        unsigned short* Xl = z == 0 ? Xql : z == 1 ? Xkl : nullptr;
        const bool isv = (z == 2);
#pragma unroll
        for (int it = 0; it < 8; ++it) {
            int ci_l = it * 4 + (tid >> 6);
            int pos = (tid & 63) * 4;
            const float4 rd =
                *(const float4*)&X[(size_t)(n * 512 + cig * 32 + ci_l) * 256 + pos];
            uint4 u;
            u.x = isv ? (unsigned)f2bf(rd.x) : pack_hl_f16(rd.x);
            u.y = isv ? (unsigned)f2bf(rd.y) : pack_hl_f16(rd.y);
            u.z = isv ? (unsigned)f2bf(rd.z) : pack_hl_f16(rd.z);
            u.w = isv ? (unsigned)f2bf(rd.w) : pack_hl_f16(rd.w);
            *(uint4*)&U[ci_l * 256 + pos] = u;
        }
        __syncthreads();
#pragma unroll
        for (int it = 0; it < 4; ++it) {
            int pos = it * 64 + (tid >> 2);
            int ci8 = (tid & 3) * 8;
            short8 h8, l8;
#pragma unroll
            for (int j = 0; j < 8; ++j) {
                unsigned int u = U[(ci8 + j) * 256 + pos];
                h8[j] = (short)(u & 0xffffu);
                l8[j] = (short)(u >> 16);
            }
            int yy = (pos >> 3) + 1, xx = (pos & 7) + 1;
            size_t o = (size_t)((n * 34 + yy) * 10 + xx) * 512 + cig * 32 + ci8;
            *(short8*)&Xh[o] = h8;
            if (Xl) *(short8*)&Xl[o] = l8;
        }
    } else if (b < 3584) {
        // ---- weight prep: [co][ci][tap] fp32 -> [co][tap][ci];
        //      Wq/Wk single f16, Wv/Wo single bf16 ----
        const int bl = b - 1536;
        const int co = bl & 511, z = bl >> 9;
        const float* W = z == 0 ? Wq : z == 1 ? Wk : z == 2 ? Wv : Wo;
        unsigned short* Wh = z == 0 ? Wqh : z == 1 ? Wkh : z == 2 ? Wvh : Woh;
        const bool f16w = (z < 2);
        const float* Wc = W + co * 4608;
#pragma unroll
        for (int it = 0; it < 9; ++it) {
            int p = it * 256 + tid;
            float2 rd = *(const float2*)&Wc[p * 2];
            int e0 = p * 2;
            int ci0 = e0 / 9, t0 = e0 - ci0 * 9;
            U[t0 * 512 + ci0] = f16w ? f2h(rd.x) : f2bf(rd.x);
            int e1 = e0 + 1;
            int ci1 = e1 / 9, t1 = e1 - ci1 * 9;
            U[t1 * 512 + ci1] = f16w ? f2h(rd.y) : f2bf(rd.y);
        }
        __syncthreads();
        unsigned short* Whc = Wh + co * 4608;
#pragma unroll
        for (int it = 0; it < 18; ++it) {
            int j = it * 256 + tid;
            Whc[j] = (unsigned short)U[j];
        }
    } else {
        // ---- halo zeroing: 84 halo cells per (array, n) ----
        const int w = tid >> 6, l = tid & 63;
        int job = (b - 3584) * 4 + w;        // 13440 jobs = 5 arrays * 32 n * 84
        int a = job / 2688;
        int r = job - a * 2688;
        int n = r / 84;
        int ii = r - n * 84;
        unsigned short* arr = a == 0 ? Xqh : a == 1 ? Xql : a == 2 ? Xkh
                                     : a == 3 ? Xkl : Xvh;
        int cell;
        if (ii < 11)      cell = ii;
        else if (ii < 73) { int j = ii - 11; cell = 19 + (j >> 1) * 10 + (j & 1); }
        else              cell = 329 + (ii - 73);
        short8 z8 = {0, 0, 0, 0, 0, 0, 0, 0};
        *(short8*)&arr[(size_t)(n * 340 + cell) * 512 + l * 8] = z8;
    }
}

// ---- merged QKV conv: z=0 Q (f16 2-pass, hi/lo out), z=1 K (f16 2-pass,
//      single out), z=2 V (bf16 1-pass -> Vt) ----
__global__ __launch_bounds__(256) void k_conv_qkv_all(
        const unsigned short* __restrict__ Xqh, const unsigned short* __restrict__ Xql,
        const unsigned short* __restrict__ Xkh, const unsigned short* __restrict__ Xkl,
        const unsigned short* __restrict__ Xvh,
        const unsigned short* __restrict__ Wqh_, const unsigned short* __restrict__ Wkh_,
        const unsigned short* __restrict__ Wvh_,
        const float* __restrict__ bq, const float* __restrict__ bk,
        const float* __restrict__ bv,
        unsigned short* __restrict__ Qh, unsigned short* __restrict__ Ql,
        unsigned short* __restrict__ Kh,
        unsigned short* __restrict__ Vt) {
    __shared__ __align__(16) short Ah[4096], Al[4096], Bh[4096];   // 24KB
    const int z = blockIdx.z;
    const bool split = (z < 2);
    const unsigned short* Xh = z == 0 ? Xqh : z == 1 ? Xkh : Xvh;
    const unsigned short* Xl = z == 0 ? Xql : Xkl;
    const unsigned short* Wh = z == 0 ? Wqh_ : z == 1 ? Wkh_ : Wvh_;
    const float* bias = z == 0 ? bq : z == 1 ? bk : bv;
    unsigned short* Oh = z == 0 ? Qh : Kh;

    const int tid = threadIdx.x;
    const int w = tid >> 6, l = tid & 63;
    const int n   = blockIdx.x >> 1;
    const int p0  = (blockIdx.x & 1) * 128;
    const int co0 = blockIdx.y * 128;
    const int lm = l & 15, lq = l >> 4;

    int arow[2], brow[2];
#pragma unroll
    for (int i = 0; i < 2; ++i) {
        int rr = w * 32 + i * 16 + (l >> 2);
        int c  = (l & 3) ^ ((rr >> 1) & 3);             // XOR bank swizzle
        int px = p0 + rr;
        int y = px >> 3, x = px & 7;
        arow[i] = ((n * 34 + y + 1) * 10 + (x + 1)) * 512 + c * 8;
        brow[i] = (co0 + rr) * 4608 + c * 8;
    }
    const int lds0 = w * 2048, lds1 = w * 2048 + 1024;

    int aoff[4], boff[4];
#pragma unroll
    for (int mi = 0; mi < 4; ++mi) {
        int row = (w & 1) * 64 + mi * 16 + lm;
        aoff[mi] = row * 32 + (lq ^ ((row >> 1) & 3)) * 8;
    }
#pragma unroll
    for (int ni = 0; ni < 4; ++ni) {
        int row = (w >> 1) * 64 + ni * 16 + lm;
        boff[ni] = row * 32 + (lq ^ ((row >> 1) & 3)) * 8;
    }

    f32x4 acc[4][4];
#pragma unroll
    for (int ni = 0; ni < 4; ++ni) {
        float b = bias[co0 + (w >> 1) * 64 + ni * 16 + lm];
#pragma unroll
        for (int mi = 0; mi < 4; ++mi) acc[mi][ni] = (f32x4){b, b, b, b};
    }

    for (int tap = 0; tap < 9; ++tap) {
        const int tapoff = ((tap / 3 - 1) * 10 + (tap % 3 - 1)) * 512;
        const int wb = tap * 512;
        for (int ci0 = 0; ci0 < 512; ci0 += 32) {
            int a0 = arow[0] + tapoff + ci0, a1 = arow[1] + tapoff + ci0;
            int b0 = brow[0] + wb + ci0,     b1 = brow[1] + wb + ci0;
            gl_lds16(Xh + a0, (char*)Ah + lds0);
            gl_lds16(Xh + a1, (char*)Ah + lds1);
            gl_lds16(Wh + b0, (char*)Bh + lds0);
            gl_lds16(Wh + b1, (char*)Bh + lds1);
            if (split) {
                gl_lds16(Xl + a0, (char*)Al + lds0);
                gl_lds16(Xl + a1, (char*)Al + lds1);
            }
            __syncthreads();
            __builtin_amdgcn_s_setprio(1);
            if (split) {
                half8 ah[4], bh[4];
#pragma unroll
                for (int mi = 0; mi < 4; ++mi) ah[mi] = *(const half8*)&Ah[aoff[mi]];
#pragma unroll
                for (int ni = 0; ni < 4; ++ni) bh[ni] = *(const half8*)&Bh[boff[ni]];
#pragma unroll
                for (int mi = 0; mi < 4; ++mi)
#pragma unroll
                    for (int ni = 0; ni < 4; ++ni)
                        acc[mi][ni] = MFMA16F(ah[mi], bh[ni], acc[mi][ni]);
                half8 alv[4];
#pragma unroll
                for (int mi = 0; mi < 4; ++mi) alv[mi] = *(const half8*)&Al[aoff[mi]];
#pragma unroll
                for (int mi = 0; mi < 4; ++mi)
#pragma unroll
                    for (int ni = 0; ni < 4; ++ni)
                        acc[mi][ni] = MFMA16F(alv[mi], bh[ni], acc[mi][ni]);
            } else {
                short8 ah[4], bh[4];
#pragma unroll
                for (int mi = 0; mi < 4; ++mi) ah[mi] = *(const short8*)&Ah[aoff[mi]];
#pragma unroll
                for (int ni = 0; ni < 4; ++ni) bh[ni] = *(const short8*)&Bh[boff[ni]];
#pragma unroll
                for (int mi = 0; mi < 4; ++mi)
#pragma unroll
                    for (int ni = 0; ni < 4; ++ni)
                        acc[mi][ni] = MFMA16(ah[mi], bh[ni], acc[mi][ni]);
            }
            __builtin_amdgcn_s_setprio(0);
            __syncthreads();
        }
    }

    const int hh = n >> 2, nl = n & 3;
    const int pxbase = p0 + (w & 1) * 64 + lq * 4;
    const int x0q = pxbase & 7;
#pragma unroll
    for (int mi = 0; mi < 4; ++mi) {
        int px = pxbase + mi * 16;
        int y = px >> 3;
#pragma unroll
        for (int ni = 0; ni < 4; ++ni) {
            int co = co0 + (w >> 1) * 64 + ni * 16 + lm;
            int nn = nl * 8 + (co >> 6);
            int dd = (co & 63) * 8 + (y >> 2);
            int t0 = hh * 32 + (y & 3) * 8 + x0q;
            if (z == 0) {                      // Q: f16 hi + f16 lo
                short4v hv, lv;
#pragma unroll
                for (int r = 0; r < 4; ++r) {
                    float xv = acc[mi][ni][r];
                    unsigned short hb = f2h(xv);
                    hv[r] = (short)hb;
                    lv[r] = (short)f2h(xv - h2f(hb));
                }
                int base = (nn * 512 + dd) * 256 + t0;
                *(short4v*)&Qh[base] = hv;
                *(short4v*)&Ql[base] = lv;
            } else if (z == 1) {               // K: single f16
                short4v hv;
#pragma unroll
                for (int r = 0; r < 4; ++r) hv[r] = (short)f2h(acc[mi][ni][r]);
                *(short4v*)&Oh[(nn * 512 + dd) * 256 + t0] = hv;
            } else {                           // V: bf16 transposed
#pragma unroll
                for (int r = 0; r < 4; ++r)
                    Vt[(nn * 256 + t0 + r) * 512 + dd] = f2bf(acc[mi][ni][r]);
            }
        }
    }
}

// ---- scores: Sc[nn][q][k'] fp32 = (Qh+Ql)(f16) . K(f16), 2 passes, BK=64 ----
__global__ __launch_bounds__(256) void k_scores_mfma(
        const unsigned short* __restrict__ Qh, const unsigned short* __restrict__ Ql,
        const unsigned short* __restrict__ Kh,
        float* __restrict__ Sc) {
    __shared__ __align__(16) short Ah[8192], Al[8192], Bh[8192];   // 48KB
    const int tid = threadIdx.x;
    const int w = tid >> 6, l = tid & 63;
    const int q0 = blockIdx.x * 128, k0 = blockIdx.y * 128, nn = blockIdx.z;
    const int lm = l & 15, lq = l >> 4;
    const int r8 = l >> 3, c8 = (l & 7) ^ (l >> 3);

    int arow[4], brow[4];
#pragma unroll
    for (int j = 0; j < 4; ++j) {
        int rr = w * 32 + j * 8 + r8;
        arow[j] = (nn * 512 + q0 + rr) * 256 + c8 * 8;
        brow[j] = (nn * 512 + k0 + rr) * 256 + c8 * 8;
    }
    const int ldsW = w * 4096;       // bytes: wave's 32 rows x 128B

    int aoff[4][2], boff[4][2];
#pragma unroll
    for (int mi = 0; mi < 4; ++mi) {
        int row = (w & 1) * 64 + mi * 16 + lm;
#pragma unroll
        for (int ks = 0; ks < 2; ++ks)
            aoff[mi][ks] = row * 64 + ((((ks << 2) | lq) ^ (row & 7)) * 8);
    }
#pragma unroll
    for (int ni = 0; ni < 4; ++ni) {
        int row = (w >> 1) * 64 + ni * 16 + lm;
#pragma unroll
        for (int ks = 0; ks < 2; ++ks)
            boff[ni][ks] = row * 64 + ((((ks << 2) | lq) ^ (row & 7)) * 8);
    }

    f32x4 acc[4][4];
#pragma unroll
    for (int mi = 0; mi < 4; ++mi)
#pragma unroll
        for (int ni = 0; ni < 4; ++ni) acc[mi][ni] = (f32x4){0.f, 0.f, 0.f, 0.f};

    for (int t0 = 0; t0 < 256; t0 += 64) {
#pragma unroll
        for (int j = 0; j < 4; ++j)
            gl_lds16(Qh + arow[j] + t0, (char*)Ah + ldsW + j * 1024);
#pragma unroll
        for (int j = 0; j < 4; ++j)
            gl_lds16(Ql + arow[j] + t0, (char*)Al + ldsW + j * 1024);
#pragma unroll
        for (int j = 0; j < 4; ++j)
            gl_lds16(Kh + brow[j] + t0, (char*)Bh + ldsW + j * 1024);
        __syncthreads();
#pragma unroll
        for (int ks = 0; ks < 2; ++ks) {
            half8 ah[4], bh[4];
#pragma unroll
            for (int mi = 0; mi < 4; ++mi) ah[mi] = *(const half8*)&Ah[aoff[mi][ks]];
#pragma unroll
            for (int ni = 0; ni < 4; ++ni) bh[ni] = *(const half8*)&Bh[boff[ni][ks]];
#pragma unroll
            for (int mi = 0; mi < 4; ++mi)
#pragma unroll
                for (int ni = 0; ni < 4; ++ni)
                    acc[mi][ni] = MFMA16F(ah[mi], bh[ni], acc[mi][ni]);
            half8 alv[4];
#pragma unroll
            for (int mi = 0; mi < 4; ++mi) alv[mi] = *(const half8*)&Al[aoff[mi][ks]];
#pragma unroll
            for (int mi = 0; mi < 4; ++mi)
#pragma unroll
                for (int ni = 0; ni < 4; ++ni)
                    acc[mi][ni] = MFMA16F(alv[mi], bh[ni], acc[mi][ni]);
        }
        __syncthreads();
    }

    float* C = Sc + nn * 262144;
#pragma unroll
    for (int mi = 0; mi < 4; ++mi) {
        int qb = q0 + (w & 1) * 64 + lq * 4 + mi * 16;
#pragma unroll
        for (int ni = 0; ni < 4; ++ni) {
            int col = k0 + (w >> 1) * 64 + ni * 16 + lm;
#pragma unroll
            for (int r = 0; r < 4; ++r)
                C[(qb + r) * 512 + col] = acc[mi][ni][r];
        }
    }
}

// ---- softmax rows of 512 (+ zero Sp halo buffer) — unchanged ----
__global__ __launch_bounds__(256) void k_softmax(float* __restrict__ Sc,
                                                 unsigned short* __restrict__ Ph,
                                                 unsigned int* __restrict__ Spz) {
    unsigned zi = blockIdx.x * 256 + threadIdx.x;
    if (zi < 2641920u) Spz[zi] = 0u;           // 5,283,840 shorts of Sp
    __shared__ float red[8];
    float* p = Sc + (size_t)blockIdx.x * 512;
    unsigned short* ph = Ph + (size_t)blockIdx.x * 512;
    const int tid = threadIdx.x;
    float x0 = p[tid], x1 = p[tid + 256];
    float m = fmaxf(x0, x1);
#pragma unroll
    for (int off = 32; off; off >>= 1) m = fmaxf(m, __shfl_xor(m, off));
    if ((tid & 63) == 0) red[tid >> 6] = m;
    __syncthreads();
    m = fmaxf(fmaxf(red[0], red[1]), fmaxf(red[2], red[3]));
    float e0 = __expf(x0 - m), e1 = __expf(x1 - m);
    float s = e0 + e1;
#pragma unroll
    for (int off = 32; off; off >>= 1) s += __shfl_xor(s, off);
    if ((tid & 63) == 0) red[4 + (tid >> 6)] = s;
    __syncthreads();
    s = red[4] + red[5] + red[6] + red[7];
    float inv = 1.0f / s;
    float p0 = e0 * inv, p1 = e1 * inv;
    p[tid] = p0;
    p[tid + 256] = p1;
    ph[tid] = f2bf(p0);
    ph[tid + 256] = f2bf(p1);
}

// ---- PV: P @ V, 16x16 bf16 MFMA, BK=128; scatters into padded Sp ----
__global__ __launch_bounds__(256) void k_pv_mfma(
        const unsigned short* __restrict__ Ph, const unsigned short* __restrict__ Vt,
        unsigned short* __restrict__ Sp) {
    __shared__ __align__(16) short Ah[16384], Bh[8192];  // [128][128], [64][128]
    const int tid = threadIdx.x;
    const int w = tid >> 6, l = tid & 63;
    const int q0 = blockIdx.x * 128, t0 = blockIdx.y * 64, nn = blockIdx.z;
    const int lm = l & 15, lq = l >> 4;
    const int r4 = l >> 4, c16 = l & 15;                 // pitch-128 stage map

    int arow[8], brow[4];
#pragma unroll
    for (int j = 0; j < 8; ++j) {
        int rt = w * 32 + j * 4 + r4;
        arow[j] = (nn * 512 + q0 + rt) * 512 + ((c16 ^ (rt & 15)) * 8);
    }
#pragma unroll
    for (int j = 0; j < 4; ++j) {
        int rt = w * 16 + j * 4 + r4;
        brow[j] = (nn * 256 + t0 + rt) * 512 + ((c16 ^ (rt & 15)) * 8);
    }
    const int ldsA = w * 8192, ldsB = w * 4096;          // bytes

    int aoff[4][4], boff[2][4];
#pragma unroll
    for (int mi = 0; mi < 4; ++mi) {
        int row = (w & 1) * 64 + mi * 16 + lm;
#pragma unroll
        for (int ks = 0; ks < 4; ++ks)
            aoff[mi][ks] = row * 128 + ((((ks << 2) | lq) ^ (row & 15)) * 8);
    }
#pragma unroll
    for (int ni = 0; ni < 2; ++ni) {
        int row = (w >> 1) * 32 + ni * 16 + lm;
#pragma unroll
        for (int ks = 0; ks < 4; ++ks)
            boff[ni][ks] = row * 128 + ((((ks << 2) | lq) ^ (row & 15)) * 8);
    }

    f32x4 acc[4][2];
#pragma unroll
    for (int mi = 0; mi < 4; ++mi)
#pragma unroll
        for (int ni = 0; ni < 2; ++ni) acc[mi][ni] = (f32x4){0.f, 0.f, 0.f, 0.f};

    for (int kc = 0; kc < 512; kc += 128) {
#pragma unroll
        for (int j = 0; j < 8; ++j)
            gl_lds16(Ph + arow[j] + kc, (char*)Ah + ldsA + j * 1024);
#pragma unroll
        for (int j = 0; j < 4; ++j)
            gl_lds16(Vt + brow[j] + kc, (char*)Bh + ldsB + j * 1024);
        __syncthreads();
#pragma unroll
        for (int ks = 0; ks < 4; ++ks) {
            short8 a[4], b[2];
#pragma unroll
            for (int mi = 0; mi < 4; ++mi) a[mi] = *(const short8*)&Ah[aoff[mi][ks]];
#pragma unroll
            for (int ni = 0; ni < 2; ++ni) b[ni] = *(const short8*)&Bh[boff[ni][ks]];
#pragma unroll
            for (int mi = 0; mi < 4; ++mi)
#pragma unroll
                for (int ni = 0; ni < 2; ++ni)
                    acc[mi][ni] = MFMA16(a[mi], b[ni], acc[mi][ni]);
        }
        __syncthreads();
    }

    // scatter into Sp[b2][yy][xx][d2]:  b2=nn>>3, s2=nn&7,
    //   ww=(qp>>4)*8+((qp>>1)&7), d2=(qp&1)*256+(t&31)*8+(t>>5)
    const int b2 = nn >> 3, s2 = nn & 7;
#pragma unroll
    for (int mi = 0; mi < 4; ++mi) {
        int qb = q0 + (w & 1) * 64 + lq * 4 + mi * 16;
#pragma unroll
        for (int ni = 0; ni < 2; ++ni) {
            int tc = t0 + (w >> 1) * 32 + ni * 16 + lm;
            int d2base = (tc & 31) * 8 + (tc >> 5);
#pragma unroll
            for (int r = 0; r < 4; ++r) {
                int qp = qb + r;
                int ww = (qp >> 4) * 8 + ((qp >> 1) & 7);
                int d2 = (qp & 1) * 256 + d2base;
                Sp[((b2 * 10 + s2 + 1) * 258 + ww + 1) * 512 + d2] =
                    f2bf(acc[mi][ni][r]);
            }
        }
    }
}

// ---- output conv (16x16), BM=128 BN=64, BK=128 -> Y NCHW fp32 ----
__global__ __launch_bounds__(256) void k_conv_o_mfma(
        const unsigned short* __restrict__ Sp, const unsigned short* __restrict__ Wh,
        const float* __restrict__ bias, float* __restrict__ Y) {
    __shared__ __align__(16) short Ah[16384], Bh[8192];  // [128][128], [64][128]
    const int tid = threadIdx.x;
    const int w = tid >> 6, l = tid & 63;
    const int n   = blockIdx.x >> 4;
    const int yy  = (blockIdx.x >> 1) & 7;
    const int x0  = (blockIdx.x & 1) * 128;
    const int co0 = blockIdx.y * 64;
    const int lm = l & 15, lq = l >> 4;
    const int r4 = l >> 4, c16 = l & 15;                 // pitch-128 stage map

    int arow[8], brow[4];
#pragma unroll
    for (int j = 0; j < 8; ++j) {
        int rt = w * 32 + j * 4 + r4;
        arow[j] = ((n * 10 + yy + 1) * 258 + (x0 + rt + 1)) * 512
                  + ((c16 ^ (rt & 15)) * 8);
    }
#pragma unroll
    for (int j = 0; j < 4; ++j) {
        int rt = w * 16 + j * 4 + r4;
        brow[j] = (co0 + rt) * 4608 + ((c16 ^ (rt & 15)) * 8);
    }
    const int ldsA = w * 8192, ldsB = w * 4096;          // bytes

    int aoff[4][4], boff[2][4];
#pragma unroll
    for (int mi = 0; mi < 4; ++mi) {
        int row = (w & 1) * 64 + mi * 16 + lm;
#pragma unroll
        for (int ks = 0; ks < 4; ++ks)
            aoff[mi][ks] = row * 128 + ((((ks << 2) | lq) ^ (row & 15)) * 8);
    }
#pragma unroll
    for (int ni = 0; ni < 2; ++ni) {
        int row = (w >> 1) * 32 + ni * 16 + lm;
#pragma unroll
        for (int ks = 0; ks < 4; ++ks)
            boff[ni][ks] = row * 128 + ((((ks << 2) | lq) ^ (row & 15)) * 8);
    }

    f32x4 acc[4][2];
#pragma unroll
    for (int ni = 0; ni < 2; ++ni) {
        float b = bias[co0 + (w >> 1) * 32 + ni * 16 + lm];
#pragma unroll
        for (int mi = 0; mi < 4; ++mi) acc[mi][ni] = (f32x4){b, b, b, b};
    }

    for (int tap = 0; tap < 9; ++tap) {
        const int tapoff = ((tap / 3 - 1) * 258 + (tap % 3 - 1)) * 512;
        const int wb = tap * 512;
        for (int ci0 = 0; ci0 < 512; ci0 += 128) {
#pragma unroll
            for (int j = 0; j < 8; ++j)
                gl_lds16(Sp + arow[j] + tapoff + ci0, (char*)Ah + ldsA + j * 1024);
#pragma unroll
            for (int j = 0; j < 4; ++j)
                gl_lds16(Wh + brow[j] + wb + ci0, (char*)Bh + ldsB + j * 1024);
            __syncthreads();
#pragma unroll
            for (int ks = 0; ks < 4; ++ks) {
                short8 a[4], b[2];
#pragma unroll
                for (int mi = 0; mi < 4; ++mi)
                    a[mi] = *(const short8*)&Ah[aoff[mi][ks]];
#pragma unroll
                for (int ni = 0; ni < 2; ++ni)
                    b[ni] = *(const short8*)&Bh[boff[ni][ks]];
#pragma unroll
                for (int mi = 0; mi < 4; ++mi)
#pragma unroll
                    for (int ni = 0; ni < 2; ++ni)
                        acc[mi][ni] = MFMA16(a[mi], b[ni], acc[mi][ni]);
            }
            __syncthreads();
        }
    }

#pragma unroll
    for (int mi = 0; mi < 4; ++mi) {
        int px = x0 + (w & 1) * 64 + lq * 4 + mi * 16;
#pragma unroll
        for (int ni = 0; ni < 2; ++ni) {
            int co = co0 + (w >> 1) * 32 + ni * 16 + lm;
            *(f32x4*)&Y[n * 1048576 + co * 2048 + yy * 256 + px] = acc[mi][ni];
        }
    }
}

// ---------------------------------------------------------------------------
extern "C" void kernel_launch(void* const* d_in, const int* in_sizes, int n_in,
                              void* d_out, int out_size, void* d_ws, size_t ws_size,
                              hipStream_t stream) {
    const float* q  = (const float*)d_in[0];
    const float* k  = (const float*)d_in[1];
    const float* v  = (const float*)d_in[2];
    const float* Wq = (const float*)d_in[3];
    const float* bq = (const float*)d_in[4];
    const float* Wk = (const float*)d_in[5];
    const float* bk = (const float*)d_in[6];
    const float* Wv = (const float*)d_in[7];
    const float* bv = (const float*)d_in[8];
    const float* Wo = (const float*)d_in[9];
    const float* bo = (const float*)d_in[10];

    // ---- workspace layout (shorts); offsets kept from round 7 (Wql/Wkl/Kl
    //      slots now unused — layout risk minimized) ----
    unsigned short* W0  = (unsigned short*)d_ws;
    unsigned short* Wqh = W0;                   // 2359296 each
    unsigned short* Wkh = W0 + 4718592;
    unsigned short* Wvh = W0 + 9437184;
    unsigned short* Woh = W0 + 11796480;
    unsigned short* Xvh = W0 + 14155776;        // 5570560
    unsigned short* Qh  = W0 + 19726336;        // 4194304 each
    unsigned short* Ql  = W0 + 23920640;
    unsigned short* Kh  = W0 + 28114944;
    unsigned short* Vt  = W0 + 36503552;
    // reuses (lifetimes): Ph over Wqh.. (dead after conv; Woh intact);
    //                     Sp over Ql+Kh (dead after scores)
    unsigned short* Ph = W0;                    // 8388608 shorts
    unsigned short* Sp = W0 + 23920640;         // 5283840 shorts

    // ---- d_out scratch before final writes ----
    float* y_out = (float*)d_out;               // 4194304 floats (written last)
    float* attn  = y_out + 4194304;             // 8388608 floats (written by scores)
    unsigned short* Xqh = (unsigned short*)d_out;
    unsigned short* Xql = (unsigned short*)attn;
    unsigned short* Xkh = Xql + 5570560;
    unsigned short* Xkl = Xkh + 5570560;

    k_prep_fused<<<6944, 256, 0, stream>>>(q, k, v, Wq, Wk, Wv, Wo,
                                           Wqh, Wkh, Wvh, Woh,
                                           Xqh, Xql, Xkh, Xkl, Xvh);
    k_conv_qkv_all<<<dim3(64, 4, 3), 256, 0, stream>>>(
        Xqh, Xql, Xkh, Xkl, Xvh, Wqh, Wkh, Wvh,
        bq, bk, bv, Qh, Ql, Kh, Vt);
    k_scores_mfma<<<dim3(4, 4, 32), 256, 0, stream>>>(Qh, Ql, Kh, attn);
    k_softmax<<<16384, 256, 0, stream>>>(attn, Ph, (unsigned int*)Sp);
    k_pv_mfma<<<dim3(4, 4, 32), 256, 0, stream>>>(Ph, Vt, Sp);
    k_conv_o_mfma<<<dim3(64, 8), 256, 0, stream>>>(Sp, Woh, bo, y_out);
}

// Round 4
// 496.218 us; speedup vs baseline: 1.1466x; 1.1466x over previous
//
#include <hip/hip_runtime.h>

// ---------------------------------------------------------------------------
// MultiHeadAttention_60000693125780 — round 9
//  Round-8 post-mortem: f16 2-pass scheme was numerically fine (absmax .047
//  passed) but the MIXED f16/bf16 hot loop (if(split) + two MFMA dtypes)
//  bloated VGPR 72->104, halved occupancy (33->18%), exposed the barrier
//  drains -> conv 264->320us REGRESSION despite 5/7 work.
//  Fix: UNIFORM loop. All z (Q,K,V) do the identical 2-pass f16 K-loop
//  (stage Xh,Xl,W = 6 loads; 32 MFMA16F). V inputs/weights now f16 too
//  (more accurate than round 7's bf16 V). Pass-units 7 -> 6 with round-7
//  scheduling properties. Epilogue branches by z only.
//  Predicted: conv_qkv 225-240us (VGPR<=90, Occ ~30%), total 475-495us,
//  absmax ~= 0.047. Fallback if conv>=300 & VGPR<=90: dual-path theory
//  wrong -> revert to round 7.
// Layouts: Qh/Ql [nn][dd][t] f16 hi/lo; Kh [nn][dd][t] f16; Vt [nn][t][dd]
//  bf16; Ph [nn][q][k'] bf16; Sp padded NHWC bf16 [4][10][258][512]
// ---------------------------------------------------------------------------

typedef __attribute__((ext_vector_type(8))) short short8;
typedef __attribute__((ext_vector_type(8))) _Float16 half8;
typedef __attribute__((ext_vector_type(4))) float f32x4;
typedef __attribute__((ext_vector_type(4))) short short4v;

#define MFMA16(a, b, c) __builtin_amdgcn_mfma_f32_16x16x32_bf16((a), (b), (c), 0, 0, 0)
#define MFMA16F(a, b, c) __builtin_amdgcn_mfma_f32_16x16x32_f16((a), (b), (c), 0, 0, 0)

__device__ __forceinline__ void gl_lds16(const void* g, void* l) {
    __builtin_amdgcn_global_load_lds(
        (const __attribute__((address_space(1))) unsigned int*)g,
        (__attribute__((address_space(3))) unsigned int*)l, 16, 0, 0);
}
__device__ __forceinline__ unsigned short f2bf(float f) {
    unsigned u = __float_as_uint(f);
    return (unsigned short)((u + 0x7fffu + ((u >> 16) & 1u)) >> 16);
}
__device__ __forceinline__ float bf2f(unsigned short h) {
    return __uint_as_float(((unsigned)h) << 16);
}
__device__ __forceinline__ unsigned short f2h(float f) {
    _Float16 h = (_Float16)f;                       // RNE
    return __builtin_bit_cast(unsigned short, h);
}
__device__ __forceinline__ float h2f(unsigned short u) {
    return (float)__builtin_bit_cast(_Float16, u);
}
__device__ __forceinline__ unsigned int pack_hl_f16(float f) {
    unsigned short h = f2h(f);
    unsigned short l = f2h(f - h2f(h));
    return (unsigned)h | ((unsigned)l << 16);
}

// ---- fused prep: [0,1536) inputs | [1536,3584) weights | [3584,7616) halo
__global__ __launch_bounds__(256) void k_prep_fused(
        const float* __restrict__ q, const float* __restrict__ k,
        const float* __restrict__ v,
        const float* __restrict__ Wq, const float* __restrict__ Wk,
        const float* __restrict__ Wv, const float* __restrict__ Wo,
        unsigned short* __restrict__ Wqh, unsigned short* __restrict__ Wkh,
        unsigned short* __restrict__ Wvh, unsigned short* __restrict__ Woh,
        unsigned short* __restrict__ Xqh, unsigned short* __restrict__ Xql,
        unsigned short* __restrict__ Xkh, unsigned short* __restrict__ Xkl,
        unsigned short* __restrict__ Xvh, unsigned short* __restrict__ Xvl) {
    __shared__ __align__(16) unsigned int U[8192];
    const int b = blockIdx.x;
    const int tid = threadIdx.x;
    if (b < 1536) {
        // ---- inputs: NCHW fp32 -> padded NHWC f16 hi+lo (uniform) ----
        const int cig = b & 15, n = (b >> 4) & 31, z = b >> 9;
        const float* X = z == 0 ? q : z == 1 ? k : v;
        unsigned short* Xh = z == 0 ? Xqh : z == 1 ? Xkh : Xvh;
        unsigned short* Xl = z == 0 ? Xql : z == 1 ? Xkl : Xvl;
#pragma unroll
        for (int it = 0; it < 8; ++it) {
            int ci_l = it * 4 + (tid >> 6);
            int pos = (tid & 63) * 4;
            const float4 rd =
                *(const float4*)&X[(size_t)(n * 512 + cig * 32 + ci_l) * 256 + pos];
            uint4 u;
            u.x = pack_hl_f16(rd.x);
            u.y = pack_hl_f16(rd.y);
            u.z = pack_hl_f16(rd.z);
            u.w = pack_hl_f16(rd.w);
            *(uint4*)&U[ci_l * 256 + pos] = u;
        }
        __syncthreads();
#pragma unroll
        for (int it = 0; it < 4; ++it) {
            int pos = it * 64 + (tid >> 2);
            int ci8 = (tid & 3) * 8;
            short8 h8, l8;
#pragma unroll
            for (int j = 0; j < 8; ++j) {
                unsigned int u = U[(ci8 + j) * 256 + pos];
                h8[j] = (short)(u & 0xffffu);
                l8[j] = (short)(u >> 16);
            }
            int yy = (pos >> 3) + 1, xx = (pos & 7) + 1;
            size_t o = (size_t)((n * 34 + yy) * 10 + xx) * 512 + cig * 32 + ci8;
            *(short8*)&Xh[o] = h8;
            *(short8*)&Xl[o] = l8;
        }
    } else if (b < 3584) {
        // ---- weights: [co][ci][tap] fp32 -> [co][tap][ci];
        //      Wq/Wk/Wv single f16, Wo single bf16 ----
        const int bl = b - 1536;
        const int co = bl & 511, z = bl >> 9;
        const float* W = z == 0 ? Wq : z == 1 ? Wk : z == 2 ? Wv : Wo;
        unsigned short* Wh = z == 0 ? Wqh : z == 1 ? Wkh : z == 2 ? Wvh : Woh;
        const bool f16w = (z < 3);
        const float* Wc = W + co * 4608;
#pragma unroll
        for (int it = 0; it < 9; ++it) {
            int p = it * 256 + tid;
            float2 rd = *(const float2*)&Wc[p * 2];
            int e0 = p * 2;
            int ci0 = e0 / 9, t0 = e0 - ci0 * 9;
            U[t0 * 512 + ci0] = f16w ? f2h(rd.x) : f2bf(rd.x);
            int e1 = e0 + 1;
            int ci1 = e1 / 9, t1 = e1 - ci1 * 9;
            U[t1 * 512 + ci1] = f16w ? f2h(rd.y) : f2bf(rd.y);
        }
        __syncthreads();
        unsigned short* Whc = Wh + co * 4608;
#pragma unroll
        for (int it = 0; it < 18; ++it) {
            int j = it * 256 + tid;
            Whc[j] = (unsigned short)U[j];
        }
    } else {
        // ---- halo zeroing: 84 halo cells per (array, n), 6 arrays ----
        const int w = tid >> 6, l = tid & 63;
        int job = (b - 3584) * 4 + w;        // 16128 jobs = 6 arrays * 32 n * 84
        int a = job / 2688;
        int r = job - a * 2688;
        int n = r / 84;
        int ii = r - n * 84;
        unsigned short* arr = a == 0 ? Xqh : a == 1 ? Xql : a == 2 ? Xkh
                                     : a == 3 ? Xkl : a == 4 ? Xvh : Xvl;
        int cell;
        if (ii < 11)      cell = ii;
        else if (ii < 73) { int j = ii - 11; cell = 19 + (j >> 1) * 10 + (j & 1); }
        else              cell = 329 + (ii - 73);
        short8 z8 = {0, 0, 0, 0, 0, 0, 0, 0};
        *(short8*)&arr[(size_t)(n * 340 + cell) * 512 + l * 8] = z8;
    }
}

// ---- merged QKV conv: UNIFORM 2-pass f16 K-loop for all z.
//      Epilogue: z=0 Q -> f16 hi/lo; z=1 K -> f16; z=2 V -> bf16 Vt ----
__global__ __launch_bounds__(256) void k_conv_qkv_all(
        const unsigned short* __restrict__ Xqh, const unsigned short* __restrict__ Xql,
        const unsigned short* __restrict__ Xkh, const unsigned short* __restrict__ Xkl,
        const unsigned short* __restrict__ Xvh, const unsigned short* __restrict__ Xvl,
        const unsigned short* __restrict__ Wqh_, const unsigned short* __restrict__ Wkh_,
        const unsigned short* __restrict__ Wvh_,
        const float* __restrict__ bq, const float* __restrict__ bk,
        const float* __restrict__ bv,
        unsigned short* __restrict__ Qh, unsigned short* __restrict__ Ql,
        unsigned short* __restrict__ Kh,
        unsigned short* __restrict__ Vt) {
    __shared__ __align__(16) short Ah[4096], Al[4096], Bh[4096];   // 24KB
    const int z = blockIdx.z;
    const unsigned short* Xh = z == 0 ? Xqh : z == 1 ? Xkh : Xvh;
    const unsigned short* Xl = z == 0 ? Xql : z == 1 ? Xkl : Xvl;
    const unsigned short* Wh = z == 0 ? Wqh_ : z == 1 ? Wkh_ : Wvh_;
    const float* bias = z == 0 ? bq : z == 1 ? bk : bv;

    const int tid = threadIdx.x;
    const int w = tid >> 6, l = tid & 63;
    const int n   = blockIdx.x >> 1;
    const int p0  = (blockIdx.x & 1) * 128;
    const int co0 = blockIdx.y * 128;
    const int lm = l & 15, lq = l >> 4;

    int arow[2], brow[2];
#pragma unroll
    for (int i = 0; i < 2; ++i) {
        int rr = w * 32 + i * 16 + (l >> 2);
        int c  = (l & 3) ^ ((rr >> 1) & 3);             // XOR bank swizzle
        int px = p0 + rr;
        int y = px >> 3, x = px & 7;
        arow[i] = ((n * 34 + y + 1) * 10 + (x + 1)) * 512 + c * 8;
        brow[i] = (co0 + rr) * 4608 + c * 8;
    }
    const int lds0 = w * 2048, lds1 = w * 2048 + 1024;

    int aoff[4], boff[4];
#pragma unroll
    for (int mi = 0; mi < 4; ++mi) {
        int row = (w & 1) * 64 + mi * 16 + lm;
        aoff[mi] = row * 32 + (lq ^ ((row >> 1) & 3)) * 8;
    }
#pragma unroll
    for (int ni = 0; ni < 4; ++ni) {
        int row = (w >> 1) * 64 + ni * 16 + lm;
        boff[ni] = row * 32 + (lq ^ ((row >> 1) & 3)) * 8;
    }

    f32x4 acc[4][4];
#pragma unroll
    for (int ni = 0; ni < 4; ++ni) {
        float b = bias[co0 + (w >> 1) * 64 + ni * 16 + lm];
#pragma unroll
        for (int mi = 0; mi < 4; ++mi) acc[mi][ni] = (f32x4){b, b, b, b};
    }

    for (int tap = 0; tap < 9; ++tap) {
        const int tapoff = ((tap / 3 - 1) * 10 + (tap % 3 - 1)) * 512;
        const int wb = tap * 512;
        for (int ci0 = 0; ci0 < 512; ci0 += 32) {
            int a0 = arow[0] + tapoff + ci0, a1 = arow[1] + tapoff + ci0;
            int b0 = brow[0] + wb + ci0,     b1 = brow[1] + wb + ci0;
            gl_lds16(Xh + a0, (char*)Ah + lds0);
            gl_lds16(Xh + a1, (char*)Ah + lds1);
            gl_lds16(Xl + a0, (char*)Al + lds0);
            gl_lds16(Xl + a1, (char*)Al + lds1);
            gl_lds16(Wh + b0, (char*)Bh + lds0);
            gl_lds16(Wh + b1, (char*)Bh + lds1);
            __syncthreads();
            __builtin_amdgcn_s_setprio(1);
            half8 ah[4], bh[4];
#pragma unroll
            for (int mi = 0; mi < 4; ++mi) ah[mi] = *(const half8*)&Ah[aoff[mi]];
#pragma unroll
            for (int ni = 0; ni < 4; ++ni) bh[ni] = *(const half8*)&Bh[boff[ni]];
#pragma unroll
            for (int mi = 0; mi < 4; ++mi)
#pragma unroll
                for (int ni = 0; ni < 4; ++ni)
                    acc[mi][ni] = MFMA16F(ah[mi], bh[ni], acc[mi][ni]);
            half8 alv[4];
#pragma unroll
            for (int mi = 0; mi < 4; ++mi) alv[mi] = *(const half8*)&Al[aoff[mi]];
#pragma unroll
            for (int mi = 0; mi < 4; ++mi)
#pragma unroll
                for (int ni = 0; ni < 4; ++ni)
                    acc[mi][ni] = MFMA16F(alv[mi], bh[ni], acc[mi][ni]);
            __builtin_amdgcn_s_setprio(0);
            __syncthreads();
        }
    }

    const int hh = n >> 2, nl = n & 3;
    const int pxbase = p0 + (w & 1) * 64 + lq * 4;
    const int x0q = pxbase & 7;
#pragma unroll
    for (int mi = 0; mi < 4; ++mi) {
        int px = pxbase + mi * 16;
        int y = px >> 3;
#pragma unroll
        for (int ni = 0; ni < 4; ++ni) {
            int co = co0 + (w >> 1) * 64 + ni * 16 + lm;
            int nn = nl * 8 + (co >> 6);
            int dd = (co & 63) * 8 + (y >> 2);
            int t0 = hh * 32 + (y & 3) * 8 + x0q;
            if (z == 0) {                      // Q: f16 hi + f16 lo
                short4v hv, lv;
#pragma unroll
                for (int r = 0; r < 4; ++r) {
                    float xv = acc[mi][ni][r];
                    unsigned short hb = f2h(xv);
                    hv[r] = (short)hb;
                    lv[r] = (short)f2h(xv - h2f(hb));
                }
                int base = (nn * 512 + dd) * 256 + t0;
                *(short4v*)&Qh[base] = hv;
                *(short4v*)&Ql[base] = lv;
            } else if (z == 1) {               // K: single f16
                short4v hv;
#pragma unroll
                for (int r = 0; r < 4; ++r) hv[r] = (short)f2h(acc[mi][ni][r]);
                *(short4v*)&Kh[(nn * 512 + dd) * 256 + t0] = hv;
            } else {                           // V: bf16 transposed
#pragma unroll
                for (int r = 0; r < 4; ++r)
                    Vt[(nn * 256 + t0 + r) * 512 + dd] = f2bf(acc[mi][ni][r]);
            }
        }
    }
}

// ---- scores: Sc[nn][q][k'] fp32 = (Qh+Ql)(f16) . K(f16), 2 passes, BK=64 ----
__global__ __launch_bounds__(256) void k_scores_mfma(
        const unsigned short* __restrict__ Qh, const unsigned short* __restrict__ Ql,
        const unsigned short* __restrict__ Kh,
        float* __restrict__ Sc) {
    __shared__ __align__(16) short Ah[8192], Al[8192], Bh[8192];   // 48KB
    const int tid = threadIdx.x;
    const int w = tid >> 6, l = tid & 63;
    const int q0 = blockIdx.x * 128, k0 = blockIdx.y * 128, nn = blockIdx.z;
    const int lm = l & 15, lq = l >> 4;
    const int r8 = l >> 3, c8 = (l & 7) ^ (l >> 3);

    int arow[4], brow[4];
#pragma unroll
    for (int j = 0; j < 4; ++j) {
        int rr = w * 32 + j * 8 + r8;
        arow[j] = (nn * 512 + q0 + rr) * 256 + c8 * 8;
        brow[j] = (nn * 512 + k0 + rr) * 256 + c8 * 8;
    }
    const int ldsW = w * 4096;       // bytes: wave's 32 rows x 128B

    int aoff[4][2], boff[4][2];
#pragma unroll
    for (int mi = 0; mi < 4; ++mi) {
        int row = (w & 1) * 64 + mi * 16 + lm;
#pragma unroll
        for (int ks = 0; ks < 2; ++ks)
            aoff[mi][ks] = row * 64 + ((((ks << 2) | lq) ^ (row & 7)) * 8);
    }
#pragma unroll
    for (int ni = 0; ni < 4; ++ni) {
        int row = (w >> 1) * 64 + ni * 16 + lm;
#pragma unroll
        for (int ks = 0; ks < 2; ++ks)
            boff[ni][ks] = row * 64 + ((((ks << 2) | lq) ^ (row & 7)) * 8);
    }

    f32x4 acc[4][4];
#pragma unroll
    for (int mi = 0; mi < 4; ++mi)
#pragma unroll
        for (int ni = 0; ni < 4; ++ni) acc[mi][ni] = (f32x4){0.f, 0.f, 0.f, 0.f};

    for (int t0 = 0; t0 < 256; t0 += 64) {
#pragma unroll
        for (int j = 0; j < 4; ++j)
            gl_lds16(Qh + arow[j] + t0, (char*)Ah + ldsW + j * 1024);
#pragma unroll
        for (int j = 0; j < 4; ++j)
            gl_lds16(Ql + arow[j] + t0, (char*)Al + ldsW + j * 1024);
#pragma unroll
        for (int j = 0; j < 4; ++j)
            gl_lds16(Kh + brow[j] + t0, (char*)Bh + ldsW + j * 1024);
        __syncthreads();
#pragma unroll
        for (int ks = 0; ks < 2; ++ks) {
            half8 ah[4], bh[4];
#pragma unroll
            for (int mi = 0; mi < 4; ++mi) ah[mi] = *(const half8*)&Ah[aoff[mi][ks]];
#pragma unroll
            for (int ni = 0; ni < 4; ++ni) bh[ni] = *(const half8*)&Bh[boff[ni][ks]];
#pragma unroll
            for (int mi = 0; mi < 4; ++mi)
#pragma unroll
                for (int ni = 0; ni < 4; ++ni)
                    acc[mi][ni] = MFMA16F(ah[mi], bh[ni], acc[mi][ni]);
            half8 alv[4];
#pragma unroll
            for (int mi = 0; mi < 4; ++mi) alv[mi] = *(const half8*)&Al[aoff[mi][ks]];
#pragma unroll
            for (int mi = 0; mi < 4; ++mi)
#pragma unroll
                for (int ni = 0; ni < 4; ++ni)
                    acc[mi][ni] = MFMA16F(alv[mi], bh[ni], acc[mi][ni]);
        }
        __syncthreads();
    }

    float* C = Sc + nn * 262144;
#pragma unroll
    for (int mi = 0; mi < 4; ++mi) {
        int qb = q0 + (w & 1) * 64 + lq * 4 + mi * 16;
#pragma unroll
        for (int ni = 0; ni < 4; ++ni) {
            int col = k0 + (w >> 1) * 64 + ni * 16 + lm;
#pragma unroll
            for (int r = 0; r < 4; ++r)
                C[(qb + r) * 512 + col] = acc[mi][ni][r];
        }
    }
}

// ---- softmax rows of 512 (+ zero Sp halo buffer) — unchanged ----
__global__ __launch_bounds__(256) void k_softmax(float* __restrict__ Sc,
                                                 unsigned short* __restrict__ Ph,
                                                 unsigned int* __restrict__ Spz) {
    unsigned zi = blockIdx.x * 256 + threadIdx.x;
    if (zi < 2641920u) Spz[zi] = 0u;           // 5,283,840 shorts of Sp
    __shared__ float red[8];
    float* p = Sc + (size_t)blockIdx.x * 512;
    unsigned short* ph = Ph + (size_t)blockIdx.x * 512;
    const int tid = threadIdx.x;
    float x0 = p[tid], x1 = p[tid + 256];
    float m = fmaxf(x0, x1);
#pragma unroll
    for (int off = 32; off; off >>= 1) m = fmaxf(m, __shfl_xor(m, off));
    if ((tid & 63) == 0) red[tid >> 6] = m;
    __syncthreads();
    m = fmaxf(fmaxf(red[0], red[1]), fmaxf(red[2], red[3]));
    float e0 = __expf(x0 - m), e1 = __expf(x1 - m);
    float s = e0 + e1;
#pragma unroll
    for (int off = 32; off; off >>= 1) s += __shfl_xor(s, off);
    if ((tid & 63) == 0) red[4 + (tid >> 6)] = s;
    __syncthreads();
    s = red[4] + red[5] + red[6] + red[7];
    float inv = 1.0f / s;
    float p0 = e0 * inv, p1 = e1 * inv;
    p[tid] = p0;
    p[tid + 256] = p1;
    ph[tid] = f2bf(p0);
    ph[tid + 256] = f2bf(p1);
}

// ---- PV: P @ V, 16x16 bf16 MFMA, BK=128; scatters into padded Sp ----
__global__ __launch_bounds__(256) void k_pv_mfma(
        const unsigned short* __restrict__ Ph, const unsigned short* __restrict__ Vt,
        unsigned short* __restrict__ Sp) {
    __shared__ __align__(16) short Ah[16384], Bh[8192];  // [128][128], [64][128]
    const int tid = threadIdx.x;
    const int w = tid >> 6, l = tid & 63;
    const int q0 = blockIdx.x * 128, t0 = blockIdx.y * 64, nn = blockIdx.z;
    const int lm = l & 15, lq = l >> 4;
    const int r4 = l >> 4, c16 = l & 15;                 // pitch-128 stage map

    int arow[8], brow[4];
#pragma unroll
    for (int j = 0; j < 8; ++j) {
        int rt = w * 32 + j * 4 + r4;
        arow[j] = (nn * 512 + q0 + rt) * 512 + ((c16 ^ (rt & 15)) * 8);
    }
#pragma unroll
    for (int j = 0; j < 4; ++j) {
        int rt = w * 16 + j * 4 + r4;
        brow[j] = (nn * 256 + t0 + rt) * 512 + ((c16 ^ (rt & 15)) * 8);
    }
    const int ldsA = w * 8192, ldsB = w * 4096;          // bytes

    int aoff[4][4], boff[2][4];
#pragma unroll
    for (int mi = 0; mi < 4; ++mi) {
        int row = (w & 1) * 64 + mi * 16 + lm;
#pragma unroll
        for (int ks = 0; ks < 4; ++ks)
            aoff[mi][ks] = row * 128 + ((((ks << 2) | lq) ^ (row & 15)) * 8);
    }
#pragma unroll
    for (int ni = 0; ni < 2; ++ni) {
        int row = (w >> 1) * 32 + ni * 16 + lm;
#pragma unroll
        for (int ks = 0; ks < 4; ++ks)
            boff[ni][ks] = row * 128 + ((((ks << 2) | lq) ^ (row & 15)) * 8);
    }

    f32x4 acc[4][2];
#pragma unroll
    for (int mi = 0; mi < 4; ++mi)
#pragma unroll
        for (int ni = 0; ni < 2; ++ni) acc[mi][ni] = (f32x4){0.f, 0.f, 0.f, 0.f};

    for (int kc = 0; kc < 512; kc += 128) {
#pragma unroll
        for (int j = 0; j < 8; ++j)
            gl_lds16(Ph + arow[j] + kc, (char*)Ah + ldsA + j * 1024);
#pragma unroll
        for (int j = 0; j < 4; ++j)
            gl_lds16(Vt + brow[j] + kc, (char*)Bh + ldsB + j * 1024);
        __syncthreads();
#pragma unroll
        for (int ks = 0; ks < 4; ++ks) {
            short8 a[4], b[2];
#pragma unroll
            for (int mi = 0; mi < 4; ++mi) a[mi] = *(const short8*)&Ah[aoff[mi][ks]];
#pragma unroll
            for (int ni = 0; ni < 2; ++ni) b[ni] = *(const short8*)&Bh[boff[ni][ks]];
#pragma unroll
            for (int mi = 0; mi < 4; ++mi)
#pragma unroll
                for (int ni = 0; ni < 2; ++ni)
                    acc[mi][ni] = MFMA16(a[mi], b[ni], acc[mi][ni]);
        }
        __syncthreads();
    }

    // scatter into Sp[b2][yy][xx][d2]:  b2=nn>>3, s2=nn&7,
    //   ww=(qp>>4)*8+((qp>>1)&7), d2=(qp&1)*256+(t&31)*8+(t>>5)
    const int b2 = nn >> 3, s2 = nn & 7;
#pragma unroll
    for (int mi = 0; mi < 4; ++mi) {
        int qb = q0 + (w & 1) * 64 + lq * 4 + mi * 16;
#pragma unroll
        for (int ni = 0; ni < 2; ++ni) {
            int tc = t0 + (w >> 1) * 32 + ni * 16 + lm;
            int d2base = (tc & 31) * 8 + (tc >> 5);
#pragma unroll
            for (int r = 0; r < 4; ++r) {
                int qp = qb + r;
                int ww = (qp >> 4) * 8 + ((qp >> 1) & 7);
                int d2 = (qp & 1) * 256 + d2base;
                Sp[((b2 * 10 + s2 + 1) * 258 + ww + 1) * 512 + d2] =
                    f2bf(acc[mi][ni][r]);
            }
        }
    }
}

// ---- output conv (16x16), BM=128 BN=64, BK=128 -> Y NCHW fp32 ----
__global__ __launch_bounds__(256) void k_conv_o_mfma(
        const unsigned short* __restrict__ Sp, const unsigned short* __restrict__ Wh,
        const float* __restrict__ bias, float* __restrict__ Y) {
    __shared__ __align__(16) short Ah[16384], Bh[8192];  // [128][128], [64][128]
    const int tid = threadIdx.x;
    const int w = tid >> 6, l = tid & 63;
    const int n   = blockIdx.x >> 4;
    const int yy  = (blockIdx.x >> 1) & 7;
    const int x0  = (blockIdx.x & 1) * 128;
    const int co0 = blockIdx.y * 64;
    const int lm = l & 15, lq = l >> 4;
    const int r4 = l >> 4, c16 = l & 15;                 // pitch-128 stage map

    int arow[8], brow[4];
#pragma unroll
    for (int j = 0; j < 8; ++j) {
        int rt = w * 32 + j * 4 + r4;
        arow[j] = ((n * 10 + yy + 1) * 258 + (x0 + rt + 1)) * 512
                  + ((c16 ^ (rt & 15)) * 8);
    }
#pragma unroll
    for (int j = 0; j < 4; ++j) {
        int rt = w * 16 + j * 4 + r4;
        brow[j] = (co0 + rt) * 4608 + ((c16 ^ (rt & 15)) * 8);
    }
    const int ldsA = w * 8192, ldsB = w * 4096;          // bytes

    int aoff[4][4], boff[2][4];
#pragma unroll
    for (int mi = 0; mi < 4; ++mi) {
        int row = (w & 1) * 64 + mi * 16 + lm;
#pragma unroll
        for (int ks = 0; ks < 4; ++ks)
            aoff[mi][ks] = row * 128 + ((((ks << 2) | lq) ^ (row & 15)) * 8);
    }
#pragma unroll
    for (int ni = 0; ni < 2; ++ni) {
        int row = (w >> 1) * 32 + ni * 16 + lm;
#pragma unroll
        for (int ks = 0; ks < 4; ++ks)
            boff[ni][ks] = row * 128 + ((((ks << 2) | lq) ^ (row & 15)) * 8);
    }

    f32x4 acc[4][2];
#pragma unroll
    for (int ni = 0; ni < 2; ++ni) {
        float b = bias[co0 + (w >> 1) * 32 + ni * 16 + lm];
#pragma unroll
        for (int mi = 0; mi < 4; ++mi) acc[mi][ni] = (f32x4){b, b, b, b};
    }

    for (int tap = 0; tap < 9; ++tap) {
        const int tapoff = ((tap / 3 - 1) * 258 + (tap % 3 - 1)) * 512;
        const int wb = tap * 512;
        for (int ci0 = 0; ci0 < 512; ci0 += 128) {
#pragma unroll
            for (int j = 0; j < 8; ++j)
                gl_lds16(Sp + arow[j] + tapoff + ci0, (char*)Ah + ldsA + j * 1024);
#pragma unroll
            for (int j = 0; j < 4; ++j)
                gl_lds16(Wh + brow[j] + wb + ci0, (char*)Bh + ldsB + j * 1024);
            __syncthreads();
#pragma unroll
            for (int ks = 0; ks < 4; ++ks) {
                short8 a[4], b[2];
#pragma unroll
                for (int mi = 0; mi < 4; ++mi)
                    a[mi] = *(const short8*)&Ah[aoff[mi][ks]];
#pragma unroll
                for (int ni = 0; ni < 2; ++ni)
                    b[ni] = *(const short8*)&Bh[boff[ni][ks]];
#pragma unroll
                for (int mi = 0; mi < 4; ++mi)
#pragma unroll
                    for (int ni = 0; ni < 2; ++ni)
                        acc[mi][ni] = MFMA16(a[mi], b[ni], acc[mi][ni]);
            }
            __syncthreads();
        }
    }

#pragma unroll
    for (int mi = 0; mi < 4; ++mi) {
        int px = x0 + (w & 1) * 64 + lq * 4 + mi * 16;
#pragma unroll
        for (int ni = 0; ni < 2; ++ni) {
            int co = co0 + (w >> 1) * 32 + ni * 16 + lm;
            *(f32x4*)&Y[n * 1048576 + co * 2048 + yy * 256 + px] = acc[mi][ni];
        }
    }
}

// ---------------------------------------------------------------------------
extern "C" void kernel_launch(void* const* d_in, const int* in_sizes, int n_in,
                              void* d_out, int out_size, void* d_ws, size_t ws_size,
                              hipStream_t stream) {
    const float* q  = (const float*)d_in[0];
    const float* k  = (const float*)d_in[1];
    const float* v  = (const float*)d_in[2];
    const float* Wq = (const float*)d_in[3];
    const float* bq = (const float*)d_in[4];
    const float* Wk = (const float*)d_in[5];
    const float* bk = (const float*)d_in[6];
    const float* Wv = (const float*)d_in[7];
    const float* bv = (const float*)d_in[8];
    const float* Wo = (const float*)d_in[9];
    const float* bo = (const float*)d_in[10];

    // ---- workspace layout (shorts); repacked for Xvl, 37,355,520 total ----
    unsigned short* W0  = (unsigned short*)d_ws;
    unsigned short* Wqh = W0;                   // 2359296
    unsigned short* Wkh = W0 + 2359296;         // 2359296
    unsigned short* Wvh = W0 + 4718592;         // 2359296
    unsigned short* Xvh = W0 + 7077888;         // 5570560
    unsigned short* Xvl = W0 + 12648448;        // 5570560
    unsigned short* Woh = W0 + 18219008;        // 2359296 (alive till conv_o)
    unsigned short* Qh  = W0 + 20578304;        // 4194304
    unsigned short* Ql  = W0 + 24772608;        // 4194304
    unsigned short* Kh  = W0 + 28966912;        // 4194304
    unsigned short* Vt  = W0 + 33161216;        // 4194304 (alive till pv)
    // reuses: Ph @0 (8388608, over Wqh/Wkh/Wvh/Xvh-head — dead after conv;
    //         Woh @18219008 untouched); Sp over Qh+Ql (dead after scores)
    unsigned short* Ph = W0;                    // 8388608 shorts
    unsigned short* Sp = W0 + 20578304;         // 5283840 shorts

    // ---- d_out scratch before final writes ----
    float* y_out = (float*)d_out;               // 4194304 floats (written last)
    float* attn  = y_out + 4194304;             // 8388608 floats (written by scores)
    unsigned short* Xqh = (unsigned short*)d_out;
    unsigned short* Xql = (unsigned short*)attn;
    unsigned short* Xkh = Xql + 5570560;
    unsigned short* Xkl = Xkh + 5570560;

    k_prep_fused<<<7616, 256, 0, stream>>>(q, k, v, Wq, Wk, Wv, Wo,
                                           Wqh, Wkh, Wvh, Woh,
                                           Xqh, Xql, Xkh, Xkl, Xvh, Xvl);
    k_conv_qkv_all<<<dim3(64, 4, 3), 256, 0, stream>>>(
        Xqh, Xql, Xkh, Xkl, Xvh, Xvl, Wqh, Wkh, Wvh,
        bq, bk, bv, Qh, Ql, Kh, Vt);
    k_scores_mfma<<<dim3(4, 4, 32), 256, 0, stream>>>(Qh, Ql, Kh, attn);
    k_softmax<<<16384, 256, 0, stream>>>(attn, Ph, (unsigned int*)Sp);
    k_pv_mfma<<<dim3(4, 4, 32), 256, 0, stream>>>(Ph, Vt, Sp);
    k_conv_o_mfma<<<dim3(64, 8), 256, 0, stream>>>(Sp, Woh, bo, y_out);
}

// Round 5
// 412.993 us; speedup vs baseline: 1.3776x; 1.2015x over previous
//
#include <hip/hip_runtime.h>

// ---------------------------------------------------------------------------
// MultiHeadAttention_60000693125780 — round 10
//  Round-9 confirmed: uniform f16 loop restored occupancy (VGPR 72, conv 249us,
//  absmax 0.0386). Round 10 exploits the 3-array structure:
//   1) conv_qkv BK=64: 3 arrays x [128][64] f16 = 48KB LDS -> still 3 blk/CU
//      (the old 4-array bf16-split scheme needed 64KB -> m132 failure; now ok).
//      Chunk-rounds 144->72, halving the ~1us/round vmcnt(0)+barrier drain.
//      Per-64 accumulation order == two old 32-chunks (K-order preserved).
//   2) V conv 1-pass (drops lo-input pass; error ~3e-4 == Vt storage rounding).
//      Two separate uniform loop nests (z<2 / z==2), single dtype: no round-8
//      dual-path regalloc hazard. Prep no longer writes Xvl.
//   3) Tail all-f16 (Ph/Vt/Sp/Woh, MFMA16F in pv+conv_o): same cost, ~8x
//      smaller mantissa error on the PV->conv_o chain.
//  Predicted: conv 165-200us (LDS 49152, MfmaUtil 45-55), total 420-450us,
//  absmax 0.01-0.04. Fallback: conv>=230 -> revert BK; absmax>0.0625 ->
//  revert V 2-pass + bf16 tail.
// Layouts: Qh/Ql [nn][dd][t] f16 hi/lo; Kh [nn][dd][t] f16; Vt [nn][t][dd]
//  f16; Ph [nn][q][k'] f16; Sp padded NHWC f16 [4][10][258][512]
// Pitch-64 swizzle (proven 0-conflict in scores since r7): stage lane l ->
//  row l>>3, slot l&7, global chunk (l&7)^(l>>3); reader slot (ks*4+lq)^(row&7)
// ---------------------------------------------------------------------------

typedef __attribute__((ext_vector_type(8))) short short8;
typedef __attribute__((ext_vector_type(8))) _Float16 half8;
typedef __attribute__((ext_vector_type(4))) float f32x4;
typedef __attribute__((ext_vector_type(4))) short short4v;

#define MFMA16F(a, b, c) __builtin_amdgcn_mfma_f32_16x16x32_f16((a), (b), (c), 0, 0, 0)

__device__ __forceinline__ void gl_lds16(const void* g, void* l) {
    __builtin_amdgcn_global_load_lds(
        (const __attribute__((address_space(1))) unsigned int*)g,
        (__attribute__((address_space(3))) unsigned int*)l, 16, 0, 0);
}
__device__ __forceinline__ unsigned short f2h(float f) {
    _Float16 h = (_Float16)f;                       // RNE
    return __builtin_bit_cast(unsigned short, h);
}
__device__ __forceinline__ float h2f(unsigned short u) {
    return (float)__builtin_bit_cast(_Float16, u);
}
__device__ __forceinline__ unsigned int pack_hl_f16(float f) {
    unsigned short h = f2h(f);
    unsigned short l = f2h(f - h2f(h));
    return (unsigned)h | ((unsigned)l << 16);
}

// ---- fused prep: [0,1536) inputs | [1536,3584) weights | [3584,6944) halo
__global__ __launch_bounds__(256) void k_prep_fused(
        const float* __restrict__ q, const float* __restrict__ k,
        const float* __restrict__ v,
        const float* __restrict__ Wq, const float* __restrict__ Wk,
        const float* __restrict__ Wv, const float* __restrict__ Wo,
        unsigned short* __restrict__ Wqh, unsigned short* __restrict__ Wkh,
        unsigned short* __restrict__ Wvh, unsigned short* __restrict__ Woh,
        unsigned short* __restrict__ Xqh, unsigned short* __restrict__ Xql,
        unsigned short* __restrict__ Xkh, unsigned short* __restrict__ Xkl,
        unsigned short* __restrict__ Xvh) {
    __shared__ __align__(16) unsigned int U[8192];
    const int b = blockIdx.x;
    const int tid = threadIdx.x;
    if (b < 1536) {
        // ---- inputs: NCHW fp32 -> padded NHWC f16 hi(+lo for q,k) ----
        const int cig = b & 15, n = (b >> 4) & 31, z = b >> 9;
        const float* X = z == 0 ? q : z == 1 ? k : v;
        unsigned short* Xh = z == 0 ? Xqh : z == 1 ? Xkh : Xvh;
        unsigned short* Xl = z == 0 ? Xql : Xkl;
#pragma unroll
        for (int it = 0; it < 8; ++it) {
            int ci_l = it * 4 + (tid >> 6);
            int pos = (tid & 63) * 4;
            const float4 rd =
                *(const float4*)&X[(size_t)(n * 512 + cig * 32 + ci_l) * 256 + pos];
            uint4 u;
            u.x = pack_hl_f16(rd.x);
            u.y = pack_hl_f16(rd.y);
            u.z = pack_hl_f16(rd.z);
            u.w = pack_hl_f16(rd.w);
            *(uint4*)&U[ci_l * 256 + pos] = u;
        }
        __syncthreads();
#pragma unroll
        for (int it = 0; it < 4; ++it) {
            int pos = it * 64 + (tid >> 2);
            int ci8 = (tid & 3) * 8;
            short8 h8, l8;
#pragma unroll
            for (int j = 0; j < 8; ++j) {
                unsigned int u = U[(ci8 + j) * 256 + pos];
                h8[j] = (short)(u & 0xffffu);
                l8[j] = (short)(u >> 16);
            }
            int yy = (pos >> 3) + 1, xx = (pos & 7) + 1;
            size_t o = (size_t)((n * 34 + yy) * 10 + xx) * 512 + cig * 32 + ci8;
            *(short8*)&Xh[o] = h8;
            if (z < 2) *(short8*)&Xl[o] = l8;
        }
    } else if (b < 3584) {
        // ---- weights: [co][ci][tap] fp32 -> [co][tap][ci] f16 ----
        const int bl = b - 1536;
        const int co = bl & 511, z = bl >> 9;
        const float* W = z == 0 ? Wq : z == 1 ? Wk : z == 2 ? Wv : Wo;
        unsigned short* Wh = z == 0 ? Wqh : z == 1 ? Wkh : z == 2 ? Wvh : Woh;
        const float* Wc = W + co * 4608;
#pragma unroll
        for (int it = 0; it < 9; ++it) {
            int p = it * 256 + tid;
            float2 rd = *(const float2*)&Wc[p * 2];
            int e0 = p * 2;
            int ci0 = e0 / 9, t0 = e0 - ci0 * 9;
            U[t0 * 512 + ci0] = f2h(rd.x);
            int e1 = e0 + 1;
            int ci1 = e1 / 9, t1 = e1 - ci1 * 9;
            U[t1 * 512 + ci1] = f2h(rd.y);
        }
        __syncthreads();
        unsigned short* Whc = Wh + co * 4608;
#pragma unroll
        for (int it = 0; it < 18; ++it) {
            int j = it * 256 + tid;
            Whc[j] = (unsigned short)U[j];
        }
    } else {
        // ---- halo zeroing: 84 halo cells per (array, n), 5 arrays ----
        const int w = tid >> 6, l = tid & 63;
        int job = (b - 3584) * 4 + w;        // 13440 jobs = 5 arrays * 32 n * 84
        int a = job / 2688;
        int r = job - a * 2688;
        int n = r / 84;
        int ii = r - n * 84;
        unsigned short* arr = a == 0 ? Xqh : a == 1 ? Xql : a == 2 ? Xkh
                                     : a == 3 ? Xkl : Xvh;
        int cell;
        if (ii < 11)      cell = ii;
        else if (ii < 73) { int j = ii - 11; cell = 19 + (j >> 1) * 10 + (j & 1); }
        else              cell = 329 + (ii - 73);
        short8 z8 = {0, 0, 0, 0, 0, 0, 0, 0};
        *(short8*)&arr[(size_t)(n * 340 + cell) * 512 + l * 8] = z8;
    }
}

// ---- merged QKV conv, BK=64: z<2 uniform 2-pass f16; z==2 1-pass f16.
//      Epilogue: z=0 Q -> f16 hi/lo; z=1 K -> f16; z=2 V -> f16 Vt ----
__global__ __launch_bounds__(256) void k_conv_qkv_all(
        const unsigned short* __restrict__ Xqh, const unsigned short* __restrict__ Xql,
        const unsigned short* __restrict__ Xkh, const unsigned short* __restrict__ Xkl,
        const unsigned short* __restrict__ Xvh,
        const unsigned short* __restrict__ Wqh_, const unsigned short* __restrict__ Wkh_,
        const unsigned short* __restrict__ Wvh_,
        const float* __restrict__ bq, const float* __restrict__ bk,
        const float* __restrict__ bv,
        unsigned short* __restrict__ Qh, unsigned short* __restrict__ Ql,
        unsigned short* __restrict__ Kh,
        unsigned short* __restrict__ Vt) {
    __shared__ __align__(16) short Ah[8192], Al[8192], Bh[8192];   // 48KB
    const int z = blockIdx.z;
    const unsigned short* Xh = z == 0 ? Xqh : z == 1 ? Xkh : Xvh;
    const unsigned short* Xl = z == 0 ? Xql : Xkl;       // unused for z==2
    const unsigned short* Wh = z == 0 ? Wqh_ : z == 1 ? Wkh_ : Wvh_;
    const float* bias = z == 0 ? bq : z == 1 ? bk : bv;

    const int tid = threadIdx.x;
    const int w = tid >> 6, l = tid & 63;
    const int n   = blockIdx.x >> 1;
    const int p0  = (blockIdx.x & 1) * 128;
    const int co0 = blockIdx.y * 128;
    const int lm = l & 15, lq = l >> 4;
    const int r8 = l >> 3, c8 = (l & 7) ^ (l >> 3);      // pitch-64 stage map

    int arow[4], brow[4];
#pragma unroll
    for (int j = 0; j < 4; ++j) {
        int rt = w * 32 + j * 8 + r8;
        int px = p0 + rt;
        int y = px >> 3, x = px & 7;
        arow[j] = ((n * 34 + y + 1) * 10 + (x + 1)) * 512 + c8 * 8;
        brow[j] = (co0 + rt) * 4608 + c8 * 8;
    }
    const int ldsW = w * 4096;       // bytes: wave's 32 rows x 128B

    int aoff[4][2], boff[4][2];
#pragma unroll
    for (int mi = 0; mi < 4; ++mi) {
        int row = (w & 1) * 64 + mi * 16 + lm;
#pragma unroll
        for (int ks = 0; ks < 2; ++ks)
            aoff[mi][ks] = row * 64 + ((((ks << 2) | lq) ^ (row & 7)) * 8);
    }
#pragma unroll
    for (int ni = 0; ni < 4; ++ni) {
        int row = (w >> 1) * 64 + ni * 16 + lm;
#pragma unroll
        for (int ks = 0; ks < 2; ++ks)
            boff[ni][ks] = row * 64 + ((((ks << 2) | lq) ^ (row & 7)) * 8);
    }

    f32x4 acc[4][4];
#pragma unroll
    for (int ni = 0; ni < 4; ++ni) {
        float b = bias[co0 + (w >> 1) * 64 + ni * 16 + lm];
#pragma unroll
        for (int mi = 0; mi < 4; ++mi) acc[mi][ni] = (f32x4){b, b, b, b};
    }

    if (z < 2) {
        for (int tap = 0; tap < 9; ++tap) {
            const int tapoff = ((tap / 3 - 1) * 10 + (tap % 3 - 1)) * 512;
            const int wb = tap * 512;
            for (int ci0 = 0; ci0 < 512; ci0 += 64) {
#pragma unroll
                for (int j = 0; j < 4; ++j)
                    gl_lds16(Xh + arow[j] + tapoff + ci0, (char*)Ah + ldsW + j * 1024);
#pragma unroll
                for (int j = 0; j < 4; ++j)
                    gl_lds16(Xl + arow[j] + tapoff + ci0, (char*)Al + ldsW + j * 1024);
#pragma unroll
                for (int j = 0; j < 4; ++j)
                    gl_lds16(Wh + brow[j] + wb + ci0, (char*)Bh + ldsW + j * 1024);
                __syncthreads();
                __builtin_amdgcn_s_setprio(1);
#pragma unroll
                for (int ks = 0; ks < 2; ++ks) {
                    half8 ah[4], bh[4];
#pragma unroll
                    for (int mi = 0; mi < 4; ++mi)
                        ah[mi] = *(const half8*)&Ah[aoff[mi][ks]];
#pragma unroll
                    for (int ni = 0; ni < 4; ++ni)
                        bh[ni] = *(const half8*)&Bh[boff[ni][ks]];
#pragma unroll
                    for (int mi = 0; mi < 4; ++mi)
#pragma unroll
                        for (int ni = 0; ni < 4; ++ni)
                            acc[mi][ni] = MFMA16F(ah[mi], bh[ni], acc[mi][ni]);
                    half8 alv[4];
#pragma unroll
                    for (int mi = 0; mi < 4; ++mi)
                        alv[mi] = *(const half8*)&Al[aoff[mi][ks]];
#pragma unroll
                    for (int mi = 0; mi < 4; ++mi)
#pragma unroll
                        for (int ni = 0; ni < 4; ++ni)
                            acc[mi][ni] = MFMA16F(alv[mi], bh[ni], acc[mi][ni]);
                }
                __builtin_amdgcn_s_setprio(0);
                __syncthreads();
            }
        }
    } else {
        for (int tap = 0; tap < 9; ++tap) {
            const int tapoff = ((tap / 3 - 1) * 10 + (tap % 3 - 1)) * 512;
            const int wb = tap * 512;
            for (int ci0 = 0; ci0 < 512; ci0 += 64) {
#pragma unroll
                for (int j = 0; j < 4; ++j)
                    gl_lds16(Xh + arow[j] + tapoff + ci0, (char*)Ah + ldsW + j * 1024);
#pragma unroll
                for (int j = 0; j < 4; ++j)
                    gl_lds16(Wh + brow[j] + wb + ci0, (char*)Bh + ldsW + j * 1024);
                __syncthreads();
                __builtin_amdgcn_s_setprio(1);
#pragma unroll
                for (int ks = 0; ks < 2; ++ks) {
                    half8 ah[4], bh[4];
#pragma unroll
                    for (int mi = 0; mi < 4; ++mi)
                        ah[mi] = *(const half8*)&Ah[aoff[mi][ks]];
#pragma unroll
                    for (int ni = 0; ni < 4; ++ni)
                        bh[ni] = *(const half8*)&Bh[boff[ni][ks]];
#pragma unroll
                    for (int mi = 0; mi < 4; ++mi)
#pragma unroll
                        for (int ni = 0; ni < 4; ++ni)
                            acc[mi][ni] = MFMA16F(ah[mi], bh[ni], acc[mi][ni]);
                }
                __builtin_amdgcn_s_setprio(0);
                __syncthreads();
            }
        }
    }

    const int hh = n >> 2, nl = n & 3;
    const int pxbase = p0 + (w & 1) * 64 + lq * 4;
    const int x0q = pxbase & 7;
#pragma unroll
    for (int mi = 0; mi < 4; ++mi) {
        int px = pxbase + mi * 16;
        int y = px >> 3;
#pragma unroll
        for (int ni = 0; ni < 4; ++ni) {
            int co = co0 + (w >> 1) * 64 + ni * 16 + lm;
            int nn = nl * 8 + (co >> 6);
            int dd = (co & 63) * 8 + (y >> 2);
            int t0 = hh * 32 + (y & 3) * 8 + x0q;
            if (z == 0) {                      // Q: f16 hi + f16 lo
                short4v hv, lv;
#pragma unroll
                for (int r = 0; r < 4; ++r) {
                    float xv = acc[mi][ni][r];
                    unsigned short hb = f2h(xv);
                    hv[r] = (short)hb;
                    lv[r] = (short)f2h(xv - h2f(hb));
                }
                int base = (nn * 512 + dd) * 256 + t0;
                *(short4v*)&Qh[base] = hv;
                *(short4v*)&Ql[base] = lv;
            } else if (z == 1) {               // K: single f16
                short4v hv;
#pragma unroll
                for (int r = 0; r < 4; ++r) hv[r] = (short)f2h(acc[mi][ni][r]);
                *(short4v*)&Kh[(nn * 512 + dd) * 256 + t0] = hv;
            } else {                           // V: f16 transposed
#pragma unroll
                for (int r = 0; r < 4; ++r)
                    Vt[(nn * 256 + t0 + r) * 512 + dd] = f2h(acc[mi][ni][r]);
            }
        }
    }
}

// ---- scores: Sc[nn][q][k'] fp32 = (Qh+Ql)(f16) . K(f16), 2 passes, BK=64 ----
__global__ __launch_bounds__(256) void k_scores_mfma(
        const unsigned short* __restrict__ Qh, const unsigned short* __restrict__ Ql,
        const unsigned short* __restrict__ Kh,
        float* __restrict__ Sc) {
    __shared__ __align__(16) short Ah[8192], Al[8192], Bh[8192];   // 48KB
    const int tid = threadIdx.x;
    const int w = tid >> 6, l = tid & 63;
    const int q0 = blockIdx.x * 128, k0 = blockIdx.y * 128, nn = blockIdx.z;
    const int lm = l & 15, lq = l >> 4;
    const int r8 = l >> 3, c8 = (l & 7) ^ (l >> 3);

    int arow[4], brow[4];
#pragma unroll
    for (int j = 0; j < 4; ++j) {
        int rr = w * 32 + j * 8 + r8;
        arow[j] = (nn * 512 + q0 + rr) * 256 + c8 * 8;
        brow[j] = (nn * 512 + k0 + rr) * 256 + c8 * 8;
    }
    const int ldsW = w * 4096;       // bytes: wave's 32 rows x 128B

    int aoff[4][2], boff[4][2];
#pragma unroll
    for (int mi = 0; mi < 4; ++mi) {
        int row = (w & 1) * 64 + mi * 16 + lm;
#pragma unroll
        for (int ks = 0; ks < 2; ++ks)
            aoff[mi][ks] = row * 64 + ((((ks << 2) | lq) ^ (row & 7)) * 8);
    }
#pragma unroll
    for (int ni = 0; ni < 4; ++ni) {
        int row = (w >> 1) * 64 + ni * 16 + lm;
#pragma unroll
        for (int ks = 0; ks < 2; ++ks)
            boff[ni][ks] = row * 64 + ((((ks << 2) | lq) ^ (row & 7)) * 8);
    }

    f32x4 acc[4][4];
#pragma unroll
    for (int mi = 0; mi < 4; ++mi)
#pragma unroll
        for (int ni = 0; ni < 4; ++ni) acc[mi][ni] = (f32x4){0.f, 0.f, 0.f, 0.f};

    for (int t0 = 0; t0 < 256; t0 += 64) {
#pragma unroll
        for (int j = 0; j < 4; ++j)
            gl_lds16(Qh + arow[j] + t0, (char*)Ah + ldsW + j * 1024);
#pragma unroll
        for (int j = 0; j < 4; ++j)
            gl_lds16(Ql + arow[j] + t0, (char*)Al + ldsW + j * 1024);
#pragma unroll
        for (int j = 0; j < 4; ++j)
            gl_lds16(Kh + brow[j] + t0, (char*)Bh + ldsW + j * 1024);
        __syncthreads();
#pragma unroll
        for (int ks = 0; ks < 2; ++ks) {
            half8 ah[4], bh[4];
#pragma unroll
            for (int mi = 0; mi < 4; ++mi) ah[mi] = *(const half8*)&Ah[aoff[mi][ks]];
#pragma unroll
            for (int ni = 0; ni < 4; ++ni) bh[ni] = *(const half8*)&Bh[boff[ni][ks]];
#pragma unroll
            for (int mi = 0; mi < 4; ++mi)
#pragma unroll
                for (int ni = 0; ni < 4; ++ni)
                    acc[mi][ni] = MFMA16F(ah[mi], bh[ni], acc[mi][ni]);
            half8 alv[4];
#pragma unroll
            for (int mi = 0; mi < 4; ++mi) alv[mi] = *(const half8*)&Al[aoff[mi][ks]];
#pragma unroll
            for (int mi = 0; mi < 4; ++mi)
#pragma unroll
                for (int ni = 0; ni < 4; ++ni)
                    acc[mi][ni] = MFMA16F(alv[mi], bh[ni], acc[mi][ni]);
        }
        __syncthreads();
    }

    float* C = Sc + nn * 262144;
#pragma unroll
    for (int mi = 0; mi < 4; ++mi) {
        int qb = q0 + (w & 1) * 64 + lq * 4 + mi * 16;
#pragma unroll
        for (int ni = 0; ni < 4; ++ni) {
            int col = k0 + (w >> 1) * 64 + ni * 16 + lm;
#pragma unroll
            for (int r = 0; r < 4; ++r)
                C[(qb + r) * 512 + col] = acc[mi][ni][r];
        }
    }
}

// ---- softmax rows of 512 (+ zero Sp halo buffer); Ph now f16 ----
__global__ __launch_bounds__(256) void k_softmax(float* __restrict__ Sc,
                                                 unsigned short* __restrict__ Ph,
                                                 unsigned int* __restrict__ Spz) {
    unsigned zi = blockIdx.x * 256 + threadIdx.x;
    if (zi < 2641920u) Spz[zi] = 0u;           // 5,283,840 shorts of Sp
    __shared__ float red[8];
    float* p = Sc + (size_t)blockIdx.x * 512;
    unsigned short* ph = Ph + (size_t)blockIdx.x * 512;
    const int tid = threadIdx.x;
    float x0 = p[tid], x1 = p[tid + 256];
    float m = fmaxf(x0, x1);
#pragma unroll
    for (int off = 32; off; off >>= 1) m = fmaxf(m, __shfl_xor(m, off));
    if ((tid & 63) == 0) red[tid >> 6] = m;
    __syncthreads();
    m = fmaxf(fmaxf(red[0], red[1]), fmaxf(red[2], red[3]));
    float e0 = __expf(x0 - m), e1 = __expf(x1 - m);
    float s = e0 + e1;
#pragma unroll
    for (int off = 32; off; off >>= 1) s += __shfl_xor(s, off);
    if ((tid & 63) == 0) red[4 + (tid >> 6)] = s;
    __syncthreads();
    s = red[4] + red[5] + red[6] + red[7];
    float inv = 1.0f / s;
    float p0 = e0 * inv, p1 = e1 * inv;
    p[tid] = p0;
    p[tid + 256] = p1;
    ph[tid] = f2h(p0);
    ph[tid + 256] = f2h(p1);
}

// ---- PV: P @ V, 16x16 f16 MFMA, BK=128; scatters into padded Sp ----
__global__ __launch_bounds__(256) void k_pv_mfma(
        const unsigned short* __restrict__ Ph, const unsigned short* __restrict__ Vt,
        unsigned short* __restrict__ Sp) {
    __shared__ __align__(16) short Ah[16384], Bh[8192];  // [128][128], [64][128]
    const int tid = threadIdx.x;
    const int w = tid >> 6, l = tid & 63;
    const int q0 = blockIdx.x * 128, t0 = blockIdx.y * 64, nn = blockIdx.z;
    const int lm = l & 15, lq = l >> 4;
    const int r4 = l >> 4, c16 = l & 15;                 // pitch-128 stage map

    int arow[8], brow[4];
#pragma unroll
    for (int j = 0; j < 8; ++j) {
        int rt = w * 32 + j * 4 + r4;
        arow[j] = (nn * 512 + q0 + rt) * 512 + ((c16 ^ (rt & 15)) * 8);
    }
#pragma unroll
    for (int j = 0; j < 4; ++j) {
        int rt = w * 16 + j * 4 + r4;
        brow[j] = (nn * 256 + t0 + rt) * 512 + ((c16 ^ (rt & 15)) * 8);
    }
    const int ldsA = w * 8192, ldsB = w * 4096;          // bytes

    int aoff[4][4], boff[2][4];
#pragma unroll
    for (int mi = 0; mi < 4; ++mi) {
        int row = (w & 1) * 64 + mi * 16 + lm;
#pragma unroll
        for (int ks = 0; ks < 4; ++ks)
            aoff[mi][ks] = row * 128 + ((((ks << 2) | lq) ^ (row & 15)) * 8);
    }
#pragma unroll
    for (int ni = 0; ni < 2; ++ni) {
        int row = (w >> 1) * 32 + ni * 16 + lm;
#pragma unroll
        for (int ks = 0; ks < 4; ++ks)
            boff[ni][ks] = row * 128 + ((((ks << 2) | lq) ^ (row & 15)) * 8);
    }

    f32x4 acc[4][2];
#pragma unroll
    for (int mi = 0; mi < 4; ++mi)
#pragma unroll
        for (int ni = 0; ni < 2; ++ni) acc[mi][ni] = (f32x4){0.f, 0.f, 0.f, 0.f};

    for (int kc = 0; kc < 512; kc += 128) {
#pragma unroll
        for (int j = 0; j < 8; ++j)
            gl_lds16(Ph + arow[j] + kc, (char*)Ah + ldsA + j * 1024);
#pragma unroll
        for (int j = 0; j < 4; ++j)
            gl_lds16(Vt + brow[j] + kc, (char*)Bh + ldsB + j * 1024);
        __syncthreads();
#pragma unroll
        for (int ks = 0; ks < 4; ++ks) {
            half8 a[4], b[2];
#pragma unroll
            for (int mi = 0; mi < 4; ++mi) a[mi] = *(const half8*)&Ah[aoff[mi][ks]];
#pragma unroll
            for (int ni = 0; ni < 2; ++ni) b[ni] = *(const half8*)&Bh[boff[ni][ks]];
#pragma unroll
            for (int mi = 0; mi < 4; ++mi)
#pragma unroll
                for (int ni = 0; ni < 2; ++ni)
                    acc[mi][ni] = MFMA16F(a[mi], b[ni], acc[mi][ni]);
        }
        __syncthreads();
    }

    // scatter into Sp[b2][yy][xx][d2]:  b2=nn>>3, s2=nn&7,
    //   ww=(qp>>4)*8+((qp>>1)&7), d2=(qp&1)*256+(t&31)*8+(t>>5)
    const int b2 = nn >> 3, s2 = nn & 7;
#pragma unroll
    for (int mi = 0; mi < 4; ++mi) {
        int qb = q0 + (w & 1) * 64 + lq * 4 + mi * 16;
#pragma unroll
        for (int ni = 0; ni < 2; ++ni) {
            int tc = t0 + (w >> 1) * 32 + ni * 16 + lm;
            int d2base = (tc & 31) * 8 + (tc >> 5);
#pragma unroll
            for (int r = 0; r < 4; ++r) {
                int qp = qb + r;
                int ww = (qp >> 4) * 8 + ((qp >> 1) & 7);
                int d2 = (qp & 1) * 256 + d2base;
                Sp[((b2 * 10 + s2 + 1) * 258 + ww + 1) * 512 + d2] =
                    f2h(acc[mi][ni][r]);
            }
        }
    }
}

// ---- output conv (f16), BM=128 BN=64, BK=128 -> Y NCHW fp32 ----
__global__ __launch_bounds__(256) void k_conv_o_mfma(
        const unsigned short* __restrict__ Sp, const unsigned short* __restrict__ Wh,
        const float* __restrict__ bias, float* __restrict__ Y) {
    __shared__ __align__(16) short Ah[16384], Bh[8192];  // [128][128], [64][128]
    const int tid = threadIdx.x;
    const int w = tid >> 6, l = tid & 63;
    const int n   = blockIdx.x >> 4;
    const int yy  = (blockIdx.x >> 1) & 7;
    const int x0  = (blockIdx.x & 1) * 128;
    const int co0 = blockIdx.y * 64;
    const int lm = l & 15, lq = l >> 4;
    const int r4 = l >> 4, c16 = l & 15;                 // pitch-128 stage map

    int arow[8], brow[4];
#pragma unroll
    for (int j = 0; j < 8; ++j) {
        int rt = w * 32 + j * 4 + r4;
        arow[j] = ((n * 10 + yy + 1) * 258 + (x0 + rt + 1)) * 512
                  + ((c16 ^ (rt & 15)) * 8);
    }
#pragma unroll
    for (int j = 0; j < 4; ++j) {
        int rt = w * 16 + j * 4 + r4;
        brow[j] = (co0 + rt) * 4608 + ((c16 ^ (rt & 15)) * 8);
    }
    const int ldsA = w * 8192, ldsB = w * 4096;          // bytes

    int aoff[4][4], boff[2][4];
#pragma unroll
    for (int mi = 0; mi < 4; ++mi) {
        int row = (w & 1) * 64 + mi * 16 + lm;
#pragma unroll
        for (int ks = 0; ks < 4; ++ks)
            aoff[mi][ks] = row * 128 + ((((ks << 2) | lq) ^ (row & 15)) * 8);
    }
#pragma unroll
    for (int ni = 0; ni < 2; ++ni) {
        int row = (w >> 1) * 32 + ni * 16 + lm;
#pragma unroll
        for (int ks = 0; ks < 4; ++ks)
            boff[ni][ks] = row * 128 + ((((ks << 2) | lq) ^ (row & 15)) * 8);
    }

    f32x4 acc[4][2];
#pragma unroll
    for (int ni = 0; ni < 2; ++ni) {
        float b = bias[co0 + (w >> 1) * 32 + ni * 16 + lm];
#pragma unroll
        for (int mi = 0; mi < 4; ++mi) acc[mi][ni] = (f32x4){b, b, b, b};
    }

    for (int tap = 0; tap < 9; ++tap) {
        const int tapoff = ((tap / 3 - 1) * 258 + (tap % 3 - 1)) * 512;
        const int wb = tap * 512;
        for (int ci0 = 0; ci0 < 512; ci0 += 128) {
#pragma unroll
            for (int j = 0; j < 8; ++j)
                gl_lds16(Sp + arow[j] + tapoff + ci0, (char*)Ah + ldsA + j * 1024);
#pragma unroll
            for (int j = 0; j < 4; ++j)
                gl_lds16(Wh + brow[j] + wb + ci0, (char*)Bh + ldsB + j * 1024);
            __syncthreads();
#pragma unroll
            for (int ks = 0; ks < 4; ++ks) {
                half8 a[4], b[2];
#pragma unroll
                for (int mi = 0; mi < 4; ++mi)
                    a[mi] = *(const half8*)&Ah[aoff[mi][ks]];
#pragma unroll
                for (int ni = 0; ni < 2; ++ni)
                    b[ni] = *(const half8*)&Bh[boff[ni][ks]];
#pragma unroll
                for (int mi = 0; mi < 4; ++mi)
#pragma unroll
                    for (int ni = 0; ni < 2; ++ni)
                        acc[mi][ni] = MFMA16F(a[mi], b[ni], acc[mi][ni]);
            }
            __syncthreads();
        }
    }

#pragma unroll
    for (int mi = 0; mi < 4; ++mi) {
        int px = x0 + (w & 1) * 64 + lq * 4 + mi * 16;
#pragma unroll
        for (int ni = 0; ni < 2; ++ni) {
            int co = co0 + (w >> 1) * 32 + ni * 16 + lm;
            *(f32x4*)&Y[n * 1048576 + co * 2048 + yy * 256 + px] = acc[mi][ni];
        }
    }
}

// ---------------------------------------------------------------------------
extern "C" void kernel_launch(void* const* d_in, const int* in_sizes, int n_in,
                              void* d_out, int out_size, void* d_ws, size_t ws_size,
                              hipStream_t stream) {
    const float* q  = (const float*)d_in[0];
    const float* k  = (const float*)d_in[1];
    const float* v  = (const float*)d_in[2];
    const float* Wq = (const float*)d_in[3];
    const float* bq = (const float*)d_in[4];
    const float* Wk = (const float*)d_in[5];
    const float* bk = (const float*)d_in[6];
    const float* Wv = (const float*)d_in[7];
    const float* bv = (const float*)d_in[8];
    const float* Wo = (const float*)d_in[9];
    const float* bo = (const float*)d_in[10];

    // ---- workspace layout (shorts): round-9 offsets kept; Xvl slot dead ----
    unsigned short* W0  = (unsigned short*)d_ws;
    unsigned short* Wqh = W0;                   // 2359296
    unsigned short* Wkh = W0 + 2359296;         // 2359296
    unsigned short* Wvh = W0 + 4718592;         // 2359296
    unsigned short* Xvh = W0 + 7077888;         // 5570560
    unsigned short* Woh = W0 + 18219008;        // 2359296 (alive till conv_o)
    unsigned short* Qh  = W0 + 20578304;        // 4194304
    unsigned short* Ql  = W0 + 24772608;        // 4194304
    unsigned short* Kh  = W0 + 28966912;        // 4194304
    unsigned short* Vt  = W0 + 33161216;        // 4194304 (alive till pv)
    // reuses: Ph @0 (8388608, over Wqh/Wkh/Wvh/Xvh-head — dead after conv;
    //         Woh @18219008 untouched); Sp over Qh+Ql (dead after scores)
    unsigned short* Ph = W0;                    // 8388608 shorts
    unsigned short* Sp = W0 + 20578304;         // 5283840 shorts

    // ---- d_out scratch before final writes ----
    float* y_out = (float*)d_out;               // 4194304 floats (written last)
    float* attn  = y_out + 4194304;             // 8388608 floats (written by scores)
    unsigned short* Xqh = (unsigned short*)d_out;
    unsigned short* Xql = (unsigned short*)attn;
    unsigned short* Xkh = Xql + 5570560;
    unsigned short* Xkl = Xkh + 5570560;

    k_prep_fused<<<6944, 256, 0, stream>>>(q, k, v, Wq, Wk, Wv, Wo,
                                           Wqh, Wkh, Wvh, Woh,
                                           Xqh, Xql, Xkh, Xkl, Xvh);
    k_conv_qkv_all<<<dim3(64, 4, 3), 256, 0, stream>>>(
        Xqh, Xql, Xkh, Xkl, Xvh, Wqh, Wkh, Wvh,
        bq, bk, bv, Qh, Ql, Kh, Vt);
    k_scores_mfma<<<dim3(4, 4, 32), 256, 0, stream>>>(Qh, Ql, Kh, attn);
    k_softmax<<<16384, 256, 0, stream>>>(attn, Ph, (unsigned int*)Sp);
    k_pv_mfma<<<dim3(4, 4, 32), 256, 0, stream>>>(Ph, Vt, Sp);
    k_conv_o_mfma<<<dim3(64, 8), 256, 0, stream>>>(Sp, Woh, bo, y_out);
}

// Round 6
// 376.940 us; speedup vs baseline: 1.5094x; 1.0956x over previous
//
#include <hip/hip_runtime.h>

// ---------------------------------------------------------------------------
// MultiHeadAttention_60000693125780 — round 11
//  Round-10 confirmed BK=64 drain model (conv 249->169us, absmax 0.0361).
//  Round 11 drops the input-lo (Xl) passes: V already runs single-pass on
//  f16-rounded input (validated), K output is already single-f16 (2.4e-4),
//  so Q/K input rounding (1.2e-4 rms) only raises score error ~30% ->
//  predicted absmax ~0.045 (r8's 0.0469 passed).
//   - conv_qkv: 3 pass-units, ONE uniform single-pass f16 loop, no branch
//     in the K-loop (r8 lesson enforced structurally), 2 staged arrays,
//     32KB LDS. MFMA/round halves, drain unchanged -> ~110-140us.
//   - prep: no Xl writes (-22MB), halo 3 arrays.
//   - scores (Q hi/lo 2-pass) / softmax / pv / conv_o untouched.
//  Predicted: conv 110-140us (LDS 32768, MfmaUtil 50-60, FETCH ~160),
//  total 355-385us, absmax 0.040-0.055. Fallback: restore Xl if absmax fails.
// Layouts: Qh/Ql [nn][dd][t] f16 hi/lo; Kh [nn][dd][t] f16; Vt [nn][t][dd]
//  f16; Ph [nn][q][k'] f16; Sp padded NHWC f16 [4][10][258][512]
// Pitch-64 swizzle (0-conflict since r7): stage lane l -> row l>>3, slot l&7,
//  global chunk (l&7)^(l>>3); reader slot (ks*4+lq)^(row&7)
// ---------------------------------------------------------------------------

typedef __attribute__((ext_vector_type(8))) short short8;
typedef __attribute__((ext_vector_type(8))) _Float16 half8;
typedef __attribute__((ext_vector_type(4))) float f32x4;
typedef __attribute__((ext_vector_type(4))) short short4v;

#define MFMA16F(a, b, c) __builtin_amdgcn_mfma_f32_16x16x32_f16((a), (b), (c), 0, 0, 0)

__device__ __forceinline__ void gl_lds16(const void* g, void* l) {
    __builtin_amdgcn_global_load_lds(
        (const __attribute__((address_space(1))) unsigned int*)g,
        (__attribute__((address_space(3))) unsigned int*)l, 16, 0, 0);
}
__device__ __forceinline__ unsigned short f2h(float f) {
    _Float16 h = (_Float16)f;                       // RNE
    return __builtin_bit_cast(unsigned short, h);
}
__device__ __forceinline__ float h2f(unsigned short u) {
    return (float)__builtin_bit_cast(_Float16, u);
}

// ---- fused prep: [0,1536) inputs | [1536,3584) weights | [3584,5600) halo
__global__ __launch_bounds__(256) void k_prep_fused(
        const float* __restrict__ q, const float* __restrict__ k,
        const float* __restrict__ v,
        const float* __restrict__ Wq, const float* __restrict__ Wk,
        const float* __restrict__ Wv, const float* __restrict__ Wo,
        unsigned short* __restrict__ Wqh, unsigned short* __restrict__ Wkh,
        unsigned short* __restrict__ Wvh, unsigned short* __restrict__ Woh,
        unsigned short* __restrict__ Xqh, unsigned short* __restrict__ Xkh,
        unsigned short* __restrict__ Xvh) {
    __shared__ __align__(16) unsigned int U[8192];
    const int b = blockIdx.x;
    const int tid = threadIdx.x;
    if (b < 1536) {
        // ---- inputs: NCHW fp32 -> padded NHWC f16 (single) ----
        const int cig = b & 15, n = (b >> 4) & 31, z = b >> 9;
        const float* X = z == 0 ? q : z == 1 ? k : v;
        unsigned short* Xh = z == 0 ? Xqh : z == 1 ? Xkh : Xvh;
#pragma unroll
        for (int it = 0; it < 8; ++it) {
            int ci_l = it * 4 + (tid >> 6);
            int pos = (tid & 63) * 4;
            const float4 rd =
                *(const float4*)&X[(size_t)(n * 512 + cig * 32 + ci_l) * 256 + pos];
            uint4 u;
            u.x = f2h(rd.x);
            u.y = f2h(rd.y);
            u.z = f2h(rd.z);
            u.w = f2h(rd.w);
            *(uint4*)&U[ci_l * 256 + pos] = u;
        }
        __syncthreads();
#pragma unroll
        for (int it = 0; it < 4; ++it) {
            int pos = it * 64 + (tid >> 2);
            int ci8 = (tid & 3) * 8;
            short8 h8;
#pragma unroll
            for (int j = 0; j < 8; ++j)
                h8[j] = (short)(U[(ci8 + j) * 256 + pos] & 0xffffu);
            int yy = (pos >> 3) + 1, xx = (pos & 7) + 1;
            size_t o = (size_t)((n * 34 + yy) * 10 + xx) * 512 + cig * 32 + ci8;
            *(short8*)&Xh[o] = h8;
        }
    } else if (b < 3584) {
        // ---- weights: [co][ci][tap] fp32 -> [co][tap][ci] f16 ----
        const int bl = b - 1536;
        const int co = bl & 511, z = bl >> 9;
        const float* W = z == 0 ? Wq : z == 1 ? Wk : z == 2 ? Wv : Wo;
        unsigned short* Wh = z == 0 ? Wqh : z == 1 ? Wkh : z == 2 ? Wvh : Woh;
        const float* Wc = W + co * 4608;
#pragma unroll
        for (int it = 0; it < 9; ++it) {
            int p = it * 256 + tid;
            float2 rd = *(const float2*)&Wc[p * 2];
            int e0 = p * 2;
            int ci0 = e0 / 9, t0 = e0 - ci0 * 9;
            U[t0 * 512 + ci0] = f2h(rd.x);
            int e1 = e0 + 1;
            int ci1 = e1 / 9, t1 = e1 - ci1 * 9;
            U[t1 * 512 + ci1] = f2h(rd.y);
        }
        __syncthreads();
        unsigned short* Whc = Wh + co * 4608;
#pragma unroll
        for (int it = 0; it < 18; ++it) {
            int j = it * 256 + tid;
            Whc[j] = (unsigned short)U[j];
        }
    } else {
        // ---- halo zeroing: 84 halo cells per (array, n), 3 arrays ----
        const int w = tid >> 6, l = tid & 63;
        int job = (b - 3584) * 4 + w;        // 8064 jobs = 3 arrays * 32 n * 84
        int a = job / 2688;
        int r = job - a * 2688;
        int n = r / 84;
        int ii = r - n * 84;
        unsigned short* arr = a == 0 ? Xqh : a == 1 ? Xkh : Xvh;
        int cell;
        if (ii < 11)      cell = ii;
        else if (ii < 73) { int j = ii - 11; cell = 19 + (j >> 1) * 10 + (j & 1); }
        else              cell = 329 + (ii - 73);
        short8 z8 = {0, 0, 0, 0, 0, 0, 0, 0};
        *(short8*)&arr[(size_t)(n * 340 + cell) * 512 + l * 8] = z8;
    }
}

// ---- merged QKV conv, BK=64, ONE uniform single-pass f16 loop.
//      Epilogue: z=0 Q -> f16 hi/lo; z=1 K -> f16; z=2 V -> f16 Vt ----
__global__ __launch_bounds__(256) void k_conv_qkv_all(
        const unsigned short* __restrict__ Xqh, const unsigned short* __restrict__ Xkh,
        const unsigned short* __restrict__ Xvh,
        const unsigned short* __restrict__ Wqh_, const unsigned short* __restrict__ Wkh_,
        const unsigned short* __restrict__ Wvh_,
        const float* __restrict__ bq, const float* __restrict__ bk,
        const float* __restrict__ bv,
        unsigned short* __restrict__ Qh, unsigned short* __restrict__ Ql,
        unsigned short* __restrict__ Kh,
        unsigned short* __restrict__ Vt) {
    __shared__ __align__(16) short Ah[8192], Bh[8192];   // 32KB
    const int z = blockIdx.z;
    const unsigned short* Xh = z == 0 ? Xqh : z == 1 ? Xkh : Xvh;
    const unsigned short* Wh = z == 0 ? Wqh_ : z == 1 ? Wkh_ : Wvh_;
    const float* bias = z == 0 ? bq : z == 1 ? bk : bv;

    const int tid = threadIdx.x;
    const int w = tid >> 6, l = tid & 63;
    const int n   = blockIdx.x >> 1;
    const int p0  = (blockIdx.x & 1) * 128;
    const int co0 = blockIdx.y * 128;
    const int lm = l & 15, lq = l >> 4;
    const int r8 = l >> 3, c8 = (l & 7) ^ (l >> 3);      // pitch-64 stage map

    int arow[4], brow[4];
#pragma unroll
    for (int j = 0; j < 4; ++j) {
        int rt = w * 32 + j * 8 + r8;
        int px = p0 + rt;
        int y = px >> 3, x = px & 7;
        arow[j] = ((n * 34 + y + 1) * 10 + (x + 1)) * 512 + c8 * 8;
        brow[j] = (co0 + rt) * 4608 + c8 * 8;
    }
    const int ldsW = w * 4096;       // bytes: wave's 32 rows x 128B

    int aoff[4][2], boff[4][2];
#pragma unroll
    for (int mi = 0; mi < 4; ++mi) {
        int row = (w & 1) * 64 + mi * 16 + lm;
#pragma unroll
        for (int ks = 0; ks < 2; ++ks)
            aoff[mi][ks] = row * 64 + ((((ks << 2) | lq) ^ (row & 7)) * 8);
    }
#pragma unroll
    for (int ni = 0; ni < 4; ++ni) {
        int row = (w >> 1) * 64 + ni * 16 + lm;
#pragma unroll
        for (int ks = 0; ks < 2; ++ks)
            boff[ni][ks] = row * 64 + ((((ks << 2) | lq) ^ (row & 7)) * 8);
    }

    f32x4 acc[4][4];
#pragma unroll
    for (int ni = 0; ni < 4; ++ni) {
        float b = bias[co0 + (w >> 1) * 64 + ni * 16 + lm];
#pragma unroll
        for (int mi = 0; mi < 4; ++mi) acc[mi][ni] = (f32x4){b, b, b, b};
    }

    for (int tap = 0; tap < 9; ++tap) {
        const int tapoff = ((tap / 3 - 1) * 10 + (tap % 3 - 1)) * 512;
        const int wb = tap * 512;
        for (int ci0 = 0; ci0 < 512; ci0 += 64) {
#pragma unroll
            for (int j = 0; j < 4; ++j)
                gl_lds16(Xh + arow[j] + tapoff + ci0, (char*)Ah + ldsW + j * 1024);
#pragma unroll
            for (int j = 0; j < 4; ++j)
                gl_lds16(Wh + brow[j] + wb + ci0, (char*)Bh + ldsW + j * 1024);
            __syncthreads();
            __builtin_amdgcn_s_setprio(1);
#pragma unroll
            for (int ks = 0; ks < 2; ++ks) {
                half8 ah[4], bh[4];
#pragma unroll
                for (int mi = 0; mi < 4; ++mi)
                    ah[mi] = *(const half8*)&Ah[aoff[mi][ks]];
#pragma unroll
                for (int ni = 0; ni < 4; ++ni)
                    bh[ni] = *(const half8*)&Bh[boff[ni][ks]];
#pragma unroll
                for (int mi = 0; mi < 4; ++mi)
#pragma unroll
                    for (int ni = 0; ni < 4; ++ni)
                        acc[mi][ni] = MFMA16F(ah[mi], bh[ni], acc[mi][ni]);
            }
            __builtin_amdgcn_s_setprio(0);
            __syncthreads();
        }
    }

    const int hh = n >> 2, nl = n & 3;
    const int pxbase = p0 + (w & 1) * 64 + lq * 4;
    const int x0q = pxbase & 7;
#pragma unroll
    for (int mi = 0; mi < 4; ++mi) {
        int px = pxbase + mi * 16;
        int y = px >> 3;
#pragma unroll
        for (int ni = 0; ni < 4; ++ni) {
            int co = co0 + (w >> 1) * 64 + ni * 16 + lm;
            int nn = nl * 8 + (co >> 6);
            int dd = (co & 63) * 8 + (y >> 2);
            int t0 = hh * 32 + (y & 3) * 8 + x0q;
            if (z == 0) {                      // Q: f16 hi + f16 lo
                short4v hv, lv;
#pragma unroll
                for (int r = 0; r < 4; ++r) {
                    float xv = acc[mi][ni][r];
                    unsigned short hb = f2h(xv);
                    hv[r] = (short)hb;
                    lv[r] = (short)f2h(xv - h2f(hb));
                }
                int base = (nn * 512 + dd) * 256 + t0;
                *(short4v*)&Qh[base] = hv;
                *(short4v*)&Ql[base] = lv;
            } else if (z == 1) {               // K: single f16
                short4v hv;
#pragma unroll
                for (int r = 0; r < 4; ++r) hv[r] = (short)f2h(acc[mi][ni][r]);
                *(short4v*)&Kh[(nn * 512 + dd) * 256 + t0] = hv;
            } else {                           // V: f16 transposed
#pragma unroll
                for (int r = 0; r < 4; ++r)
                    Vt[(nn * 256 + t0 + r) * 512 + dd] = f2h(acc[mi][ni][r]);
            }
        }
    }
}

// ---- scores: Sc[nn][q][k'] fp32 = (Qh+Ql)(f16) . K(f16), 2 passes, BK=64 ----
__global__ __launch_bounds__(256) void k_scores_mfma(
        const unsigned short* __restrict__ Qh, const unsigned short* __restrict__ Ql,
        const unsigned short* __restrict__ Kh,
        float* __restrict__ Sc) {
    __shared__ __align__(16) short Ah[8192], Al[8192], Bh[8192];   // 48KB
    const int tid = threadIdx.x;
    const int w = tid >> 6, l = tid & 63;
    const int q0 = blockIdx.x * 128, k0 = blockIdx.y * 128, nn = blockIdx.z;
    const int lm = l & 15, lq = l >> 4;
    const int r8 = l >> 3, c8 = (l & 7) ^ (l >> 3);

    int arow[4], brow[4];
#pragma unroll
    for (int j = 0; j < 4; ++j) {
        int rr = w * 32 + j * 8 + r8;
        arow[j] = (nn * 512 + q0 + rr) * 256 + c8 * 8;
        brow[j] = (nn * 512 + k0 + rr) * 256 + c8 * 8;
    }
    const int ldsW = w * 4096;       // bytes: wave's 32 rows x 128B

    int aoff[4][2], boff[4][2];
#pragma unroll
    for (int mi = 0; mi < 4; ++mi) {
        int row = (w & 1) * 64 + mi * 16 + lm;
#pragma unroll
        for (int ks = 0; ks < 2; ++ks)
            aoff[mi][ks] = row * 64 + ((((ks << 2) | lq) ^ (row & 7)) * 8);
    }
#pragma unroll
    for (int ni = 0; ni < 4; ++ni) {
        int row = (w >> 1) * 64 + ni * 16 + lm;
#pragma unroll
        for (int ks = 0; ks < 2; ++ks)
            boff[ni][ks] = row * 64 + ((((ks << 2) | lq) ^ (row & 7)) * 8);
    }

    f32x4 acc[4][4];
#pragma unroll
    for (int mi = 0; mi < 4; ++mi)
#pragma unroll
        for (int ni = 0; ni < 4; ++ni) acc[mi][ni] = (f32x4){0.f, 0.f, 0.f, 0.f};

    for (int t0 = 0; t0 < 256; t0 += 64) {
#pragma unroll
        for (int j = 0; j < 4; ++j)
            gl_lds16(Qh + arow[j] + t0, (char*)Ah + ldsW + j * 1024);
#pragma unroll
        for (int j = 0; j < 4; ++j)
            gl_lds16(Ql + arow[j] + t0, (char*)Al + ldsW + j * 1024);
#pragma unroll
        for (int j = 0; j < 4; ++j)
            gl_lds16(Kh + brow[j] + t0, (char*)Bh + ldsW + j * 1024);
        __syncthreads();
#pragma unroll
        for (int ks = 0; ks < 2; ++ks) {
            half8 ah[4], bh[4];
#pragma unroll
            for (int mi = 0; mi < 4; ++mi) ah[mi] = *(const half8*)&Ah[aoff[mi][ks]];
#pragma unroll
            for (int ni = 0; ni < 4; ++ni) bh[ni] = *(const half8*)&Bh[boff[ni][ks]];
#pragma unroll
            for (int mi = 0; mi < 4; ++mi)
#pragma unroll
                for (int ni = 0; ni < 4; ++ni)
                    acc[mi][ni] = MFMA16F(ah[mi], bh[ni], acc[mi][ni]);
            half8 alv[4];
#pragma unroll
            for (int mi = 0; mi < 4; ++mi) alv[mi] = *(const half8*)&Al[aoff[mi][ks]];
#pragma unroll
            for (int mi = 0; mi < 4; ++mi)
#pragma unroll
                for (int ni = 0; ni < 4; ++ni)
                    acc[mi][ni] = MFMA16F(alv[mi], bh[ni], acc[mi][ni]);
        }
        __syncthreads();
    }

    float* C = Sc + nn * 262144;
#pragma unroll
    for (int mi = 0; mi < 4; ++mi) {
        int qb = q0 + (w & 1) * 64 + lq * 4 + mi * 16;
#pragma unroll
        for (int ni = 0; ni < 4; ++ni) {
            int col = k0 + (w >> 1) * 64 + ni * 16 + lm;
#pragma unroll
            for (int r = 0; r < 4; ++r)
                C[(qb + r) * 512 + col] = acc[mi][ni][r];
        }
    }
}

// ---- softmax rows of 512 (+ zero Sp halo buffer); Ph f16 ----
__global__ __launch_bounds__(256) void k_softmax(float* __restrict__ Sc,
                                                 unsigned short* __restrict__ Ph,
                                                 unsigned int* __restrict__ Spz) {
    unsigned zi = blockIdx.x * 256 + threadIdx.x;
    if (zi < 2641920u) Spz[zi] = 0u;           // 5,283,840 shorts of Sp
    __shared__ float red[8];
    float* p = Sc + (size_t)blockIdx.x * 512;
    unsigned short* ph = Ph + (size_t)blockIdx.x * 512;
    const int tid = threadIdx.x;
    float x0 = p[tid], x1 = p[tid + 256];
    float m = fmaxf(x0, x1);
#pragma unroll
    for (int off = 32; off; off >>= 1) m = fmaxf(m, __shfl_xor(m, off));
    if ((tid & 63) == 0) red[tid >> 6] = m;
    __syncthreads();
    m = fmaxf(fmaxf(red[0], red[1]), fmaxf(red[2], red[3]));
    float e0 = __expf(x0 - m), e1 = __expf(x1 - m);
    float s = e0 + e1;
#pragma unroll
    for (int off = 32; off; off >>= 1) s += __shfl_xor(s, off);
    if ((tid & 63) == 0) red[4 + (tid >> 6)] = s;
    __syncthreads();
    s = red[4] + red[5] + red[6] + red[7];
    float inv = 1.0f / s;
    float p0 = e0 * inv, p1 = e1 * inv;
    p[tid] = p0;
    p[tid + 256] = p1;
    ph[tid] = f2h(p0);
    ph[tid + 256] = f2h(p1);
}

// ---- PV: P @ V, 16x16 f16 MFMA, BK=128; scatters into padded Sp ----
__global__ __launch_bounds__(256) void k_pv_mfma(
        const unsigned short* __restrict__ Ph, const unsigned short* __restrict__ Vt,
        unsigned short* __restrict__ Sp) {
    __shared__ __align__(16) short Ah[16384], Bh[8192];  // [128][128], [64][128]
    const int tid = threadIdx.x;
    const int w = tid >> 6, l = tid & 63;
    const int q0 = blockIdx.x * 128, t0 = blockIdx.y * 64, nn = blockIdx.z;
    const int lm = l & 15, lq = l >> 4;
    const int r4 = l >> 4, c16 = l & 15;                 // pitch-128 stage map

    int arow[8], brow[4];
#pragma unroll
    for (int j = 0; j < 8; ++j) {
        int rt = w * 32 + j * 4 + r4;
        arow[j] = (nn * 512 + q0 + rt) * 512 + ((c16 ^ (rt & 15)) * 8);
    }
#pragma unroll
    for (int j = 0; j < 4; ++j) {
        int rt = w * 16 + j * 4 + r4;
        brow[j] = (nn * 256 + t0 + rt) * 512 + ((c16 ^ (rt & 15)) * 8);
    }
    const int ldsA = w * 8192, ldsB = w * 4096;          // bytes

    int aoff[4][4], boff[2][4];
#pragma unroll
    for (int mi = 0; mi < 4; ++mi) {
        int row = (w & 1) * 64 + mi * 16 + lm;
#pragma unroll
        for (int ks = 0; ks < 4; ++ks)
            aoff[mi][ks] = row * 128 + ((((ks << 2) | lq) ^ (row & 15)) * 8);
    }
#pragma unroll
    for (int ni = 0; ni < 2; ++ni) {
        int row = (w >> 1) * 32 + ni * 16 + lm;
#pragma unroll
        for (int ks = 0; ks < 4; ++ks)
            boff[ni][ks] = row * 128 + ((((ks << 2) | lq) ^ (row & 15)) * 8);
    }

    f32x4 acc[4][2];
#pragma unroll
    for (int mi = 0; mi < 4; ++mi)
#pragma unroll
        for (int ni = 0; ni < 2; ++ni) acc[mi][ni] = (f32x4){0.f, 0.f, 0.f, 0.f};

    for (int kc = 0; kc < 512; kc += 128) {
#pragma unroll
        for (int j = 0; j < 8; ++j)
            gl_lds16(Ph + arow[j] + kc, (char*)Ah + ldsA + j * 1024);
#pragma unroll
        for (int j = 0; j < 4; ++j)
            gl_lds16(Vt + brow[j] + kc, (char*)Bh + ldsB + j * 1024);
        __syncthreads();
#pragma unroll
        for (int ks = 0; ks < 4; ++ks) {
            half8 a[4], b[2];
#pragma unroll
            for (int mi = 0; mi < 4; ++mi) a[mi] = *(const half8*)&Ah[aoff[mi][ks]];
#pragma unroll
            for (int ni = 0; ni < 2; ++ni) b[ni] = *(const half8*)&Bh[boff[ni][ks]];
#pragma unroll
            for (int mi = 0; mi < 4; ++mi)
#pragma unroll
                for (int ni = 0; ni < 2; ++ni)
                    acc[mi][ni] = MFMA16F(a[mi], b[ni], acc[mi][ni]);
        }
        __syncthreads();
    }

    // scatter into Sp[b2][yy][xx][d2]:  b2=nn>>3, s2=nn&7,
    //   ww=(qp>>4)*8+((qp>>1)&7), d2=(qp&1)*256+(t&31)*8+(t>>5)
    const int b2 = nn >> 3, s2 = nn & 7;
#pragma unroll
    for (int mi = 0; mi < 4; ++mi) {
        int qb = q0 + (w & 1) * 64 + lq * 4 + mi * 16;
#pragma unroll
        for (int ni = 0; ni < 2; ++ni) {
            int tc = t0 + (w >> 1) * 32 + ni * 16 + lm;
            int d2base = (tc & 31) * 8 + (tc >> 5);
#pragma unroll
            for (int r = 0; r < 4; ++r) {
                int qp = qb + r;
                int ww = (qp >> 4) * 8 + ((qp >> 1) & 7);
                int d2 = (qp & 1) * 256 + d2base;
                Sp[((b2 * 10 + s2 + 1) * 258 + ww + 1) * 512 + d2] =
                    f2h(acc[mi][ni][r]);
            }
        }
    }
}

// ---- output conv (f16), BM=128 BN=64, BK=128 -> Y NCHW fp32 ----
__global__ __launch_bounds__(256) void k_conv_o_mfma(
        const unsigned short* __restrict__ Sp, const unsigned short* __restrict__ Wh,
        const float* __restrict__ bias, float* __restrict__ Y) {
    __shared__ __align__(16) short Ah[16384], Bh[8192];  // [128][128], [64][128]
    const int tid = threadIdx.x;
    const int w = tid >> 6, l = tid & 63;
    const int n   = blockIdx.x >> 4;
    const int yy  = (blockIdx.x >> 1) & 7;
    const int x0  = (blockIdx.x & 1) * 128;
    const int co0 = blockIdx.y * 64;
    const int lm = l & 15, lq = l >> 4;
    const int r4 = l >> 4, c16 = l & 15;                 // pitch-128 stage map

    int arow[8], brow[4];
#pragma unroll
    for (int j = 0; j < 8; ++j) {
        int rt = w * 32 + j * 4 + r4;
        arow[j] = ((n * 10 + yy + 1) * 258 + (x0 + rt + 1)) * 512
                  + ((c16 ^ (rt & 15)) * 8);
    }
#pragma unroll
    for (int j = 0; j < 4; ++j) {
        int rt = w * 16 + j * 4 + r4;
        brow[j] = (co0 + rt) * 4608 + ((c16 ^ (rt & 15)) * 8);
    }
    const int ldsA = w * 8192, ldsB = w * 4096;          // bytes

    int aoff[4][4], boff[2][4];
#pragma unroll
    for (int mi = 0; mi < 4; ++mi) {
        int row = (w & 1) * 64 + mi * 16 + lm;
#pragma unroll
        for (int ks = 0; ks < 4; ++ks)
            aoff[mi][ks] = row * 128 + ((((ks << 2) | lq) ^ (row & 15)) * 8);
    }
#pragma unroll
    for (int ni = 0; ni < 2; ++ni) {
        int row = (w >> 1) * 32 + ni * 16 + lm;
#pragma unroll
        for (int ks = 0; ks < 4; ++ks)
            boff[ni][ks] = row * 128 + ((((ks << 2) | lq) ^ (row & 15)) * 8);
    }

    f32x4 acc[4][2];
#pragma unroll
    for (int ni = 0; ni < 2; ++ni) {
        float b = bias[co0 + (w >> 1) * 32 + ni * 16 + lm];
#pragma unroll
        for (int mi = 0; mi < 4; ++mi) acc[mi][ni] = (f32x4){b, b, b, b};
    }

    for (int tap = 0; tap < 9; ++tap) {
        const int tapoff = ((tap / 3 - 1) * 258 + (tap % 3 - 1)) * 512;
        const int wb = tap * 512;
        for (int ci0 = 0; ci0 < 512; ci0 += 128) {
#pragma unroll
            for (int j = 0; j < 8; ++j)
                gl_lds16(Sp + arow[j] + tapoff + ci0, (char*)Ah + ldsA + j * 1024);
#pragma unroll
            for (int j = 0; j < 4; ++j)
                gl_lds16(Wh + brow[j] + wb + ci0, (char*)Bh + ldsB + j * 1024);
            __syncthreads();
#pragma unroll
            for (int ks = 0; ks < 4; ++ks) {
                half8 a[4], b[2];
#pragma unroll
                for (int mi = 0; mi < 4; ++mi)
                    a[mi] = *(const half8*)&Ah[aoff[mi][ks]];
#pragma unroll
                for (int ni = 0; ni < 2; ++ni)
                    b[ni] = *(const half8*)&Bh[boff[ni][ks]];
#pragma unroll
                for (int mi = 0; mi < 4; ++mi)
#pragma unroll
                    for (int ni = 0; ni < 2; ++ni)
                        acc[mi][ni] = MFMA16F(a[mi], b[ni], acc[mi][ni]);
            }
            __syncthreads();
        }
    }

#pragma unroll
    for (int mi = 0; mi < 4; ++mi) {
        int px = x0 + (w & 1) * 64 + lq * 4 + mi * 16;
#pragma unroll
        for (int ni = 0; ni < 2; ++ni) {
            int co = co0 + (w >> 1) * 32 + ni * 16 + lm;
            *(f32x4*)&Y[n * 1048576 + co * 2048 + yy * 256 + px] = acc[mi][ni];
        }
    }
}

// ---------------------------------------------------------------------------
extern "C" void kernel_launch(void* const* d_in, const int* in_sizes, int n_in,
                              void* d_out, int out_size, void* d_ws, size_t ws_size,
                              hipStream_t stream) {
    const float* q  = (const float*)d_in[0];
    const float* k  = (const float*)d_in[1];
    const float* v  = (const float*)d_in[2];
    const float* Wq = (const float*)d_in[3];
    const float* bq = (const float*)d_in[4];
    const float* Wk = (const float*)d_in[5];
    const float* bk = (const float*)d_in[6];
    const float* Wv = (const float*)d_in[7];
    const float* bv = (const float*)d_in[8];
    const float* Wo = (const float*)d_in[9];
    const float* bo = (const float*)d_in[10];

    // ---- workspace layout (shorts): round-10 offsets kept ----
    unsigned short* W0  = (unsigned short*)d_ws;
    unsigned short* Wqh = W0;                   // 2359296
    unsigned short* Wkh = W0 + 2359296;         // 2359296
    unsigned short* Wvh = W0 + 4718592;         // 2359296
    unsigned short* Xvh = W0 + 7077888;         // 5570560
    unsigned short* Woh = W0 + 18219008;        // 2359296 (alive till conv_o)
    unsigned short* Qh  = W0 + 20578304;        // 4194304
    unsigned short* Ql  = W0 + 24772608;        // 4194304
    unsigned short* Kh  = W0 + 28966912;        // 4194304
    unsigned short* Vt  = W0 + 33161216;        // 4194304 (alive till pv)
    // reuses: Ph @0 (8388608, over Wqh/Wkh/Wvh/Xvh-head — dead after conv;
    //         Woh @18219008 untouched); Sp over Qh+Ql (dead after scores)
    unsigned short* Ph = W0;                    // 8388608 shorts
    unsigned short* Sp = W0 + 20578304;         // 5283840 shorts

    // ---- d_out scratch before final writes ----
    float* y_out = (float*)d_out;               // 4194304 floats (written last)
    float* attn  = y_out + 4194304;             // 8388608 floats (written by scores)
    unsigned short* Xqh = (unsigned short*)d_out;
    unsigned short* Xkh = (unsigned short*)attn;

    k_prep_fused<<<5600, 256, 0, stream>>>(q, k, v, Wq, Wk, Wv, Wo,
                                           Wqh, Wkh, Wvh, Woh,
                                           Xqh, Xkh, Xvh);
    k_conv_qkv_all<<<dim3(64, 4, 3), 256, 0, stream>>>(
        Xqh, Xkh, Xvh, Wqh, Wkh, Wvh,
        bq, bk, bv, Qh, Ql, Kh, Vt);
    k_scores_mfma<<<dim3(4, 4, 32), 256, 0, stream>>>(Qh, Ql, Kh, attn);
    k_softmax<<<16384, 256, 0, stream>>>(attn, Ph, (unsigned int*)Sp);
    k_pv_mfma<<<dim3(4, 4, 32), 256, 0, stream>>>(Ph, Vt, Sp);
    k_conv_o_mfma<<<dim3(64, 8), 256, 0, stream>>>(Sp, Woh, bo, y_out);
}

// Round 7
// 367.444 us; speedup vs baseline: 1.5484x; 1.0258x over previous
//
#include <hip/hip_runtime.h>

// ---------------------------------------------------------------------------
// MultiHeadAttention_60000693125780 — round 12
//  conv_qkv accepted at structural cap (59us MFMA floor + drain; 8-phase
//  geometry-blocked at 75% fill; BK=128 = m132 regression; smaller tiles
//  break LDS-reuse balance). Attacks the flat-since-r7 ~250us "rest":
//   1) Q single-f16 (drop hi/lo): scores -> 1 pass, 2 staged arrays; conv
//      epilogue unified with K; Ql buffer dead. Score err +30% -> absmax
//      est 0.042-0.055 (r8's 0.0469 passed). Fallback: restore hi/lo.
//   2) scores BK=128 (64KB LDS, 2/CU exact): rounds 4->2, pitch-128 swizzle
//      (proven in pv/conv_o). Exact same K-accumulation order.
//   3) softmax wave-per-row: 1 wave/512-row, 8 els/lane, shuffle-only
//      (no LDS/syncthreads), grid 4096. Max exact; sum reassoc ~1e-7.
//  Predicted: conv ~127 (tripwire), total 350-365, absmax 0.040-0.055.
// Layouts: Qh,Kh [nn][dd][t] f16; Vt [nn][t][dd] f16; Ph [nn][q][k'] f16;
//          Sp padded NHWC f16 [4][10][258][512]
// Pitch-64 swizzle: stage lane l -> row l>>3, slot l&7, chunk (l&7)^(l>>3);
//   reader slot (ks*4+lq)^(row&7).  Pitch-128: stage l -> row l>>4, chunk
//   (l&15)^(row&15); reader (ks*4+lq)^(row&15).
// ---------------------------------------------------------------------------

typedef __attribute__((ext_vector_type(8))) short short8;
typedef __attribute__((ext_vector_type(8))) _Float16 half8;
typedef __attribute__((ext_vector_type(4))) float f32x4;
typedef __attribute__((ext_vector_type(4))) short short4v;

#define MFMA16F(a, b, c) __builtin_amdgcn_mfma_f32_16x16x32_f16((a), (b), (c), 0, 0, 0)

__device__ __forceinline__ void gl_lds16(const void* g, void* l) {
    __builtin_amdgcn_global_load_lds(
        (const __attribute__((address_space(1))) unsigned int*)g,
        (__attribute__((address_space(3))) unsigned int*)l, 16, 0, 0);
}
__device__ __forceinline__ unsigned short f2h(float f) {
    _Float16 h = (_Float16)f;                       // RNE
    return __builtin_bit_cast(unsigned short, h);
}

// ---- fused prep: [0,1536) inputs | [1536,3584) weights | [3584,5600) halo
__global__ __launch_bounds__(256) void k_prep_fused(
        const float* __restrict__ q, const float* __restrict__ k,
        const float* __restrict__ v,
        const float* __restrict__ Wq, const float* __restrict__ Wk,
        const float* __restrict__ Wv, const float* __restrict__ Wo,
        unsigned short* __restrict__ Wqh, unsigned short* __restrict__ Wkh,
        unsigned short* __restrict__ Wvh, unsigned short* __restrict__ Woh,
        unsigned short* __restrict__ Xqh, unsigned short* __restrict__ Xkh,
        unsigned short* __restrict__ Xvh) {
    __shared__ __align__(16) unsigned int U[8192];
    const int b = blockIdx.x;
    const int tid = threadIdx.x;
    if (b < 1536) {
        // ---- inputs: NCHW fp32 -> padded NHWC f16 (single) ----
        const int cig = b & 15, n = (b >> 4) & 31, z = b >> 9;
        const float* X = z == 0 ? q : z == 1 ? k : v;
        unsigned short* Xh = z == 0 ? Xqh : z == 1 ? Xkh : Xvh;
#pragma unroll
        for (int it = 0; it < 8; ++it) {
            int ci_l = it * 4 + (tid >> 6);
            int pos = (tid & 63) * 4;
            const float4 rd =
                *(const float4*)&X[(size_t)(n * 512 + cig * 32 + ci_l) * 256 + pos];
            uint4 u;
            u.x = f2h(rd.x);
            u.y = f2h(rd.y);
            u.z = f2h(rd.z);
            u.w = f2h(rd.w);
            *(uint4*)&U[ci_l * 256 + pos] = u;
        }
        __syncthreads();
#pragma unroll
        for (int it = 0; it < 4; ++it) {
            int pos = it * 64 + (tid >> 2);
            int ci8 = (tid & 3) * 8;
            short8 h8;
#pragma unroll
            for (int j = 0; j < 8; ++j)
                h8[j] = (short)(U[(ci8 + j) * 256 + pos] & 0xffffu);
            int yy = (pos >> 3) + 1, xx = (pos & 7) + 1;
            size_t o = (size_t)((n * 34 + yy) * 10 + xx) * 512 + cig * 32 + ci8;
            *(short8*)&Xh[o] = h8;
        }
    } else if (b < 3584) {
        // ---- weights: [co][ci][tap] fp32 -> [co][tap][ci] f16 ----
        const int bl = b - 1536;
        const int co = bl & 511, z = bl >> 9;
        const float* W = z == 0 ? Wq : z == 1 ? Wk : z == 2 ? Wv : Wo;
        unsigned short* Wh = z == 0 ? Wqh : z == 1 ? Wkh : z == 2 ? Wvh : Woh;
        const float* Wc = W + co * 4608;
#pragma unroll
        for (int it = 0; it < 9; ++it) {
            int p = it * 256 + tid;
            float2 rd = *(const float2*)&Wc[p * 2];
            int e0 = p * 2;
            int ci0 = e0 / 9, t0 = e0 - ci0 * 9;
            U[t0 * 512 + ci0] = f2h(rd.x);
            int e1 = e0 + 1;
            int ci1 = e1 / 9, t1 = e1 - ci1 * 9;
            U[t1 * 512 + ci1] = f2h(rd.y);
        }
        __syncthreads();
        unsigned short* Whc = Wh + co * 4608;
#pragma unroll
        for (int it = 0; it < 18; ++it) {
            int j = it * 256 + tid;
            Whc[j] = (unsigned short)U[j];
        }
    } else {
        // ---- halo zeroing: 84 halo cells per (array, n), 3 arrays ----
        const int w = tid >> 6, l = tid & 63;
        int job = (b - 3584) * 4 + w;        // 8064 jobs = 3 arrays * 32 n * 84
        int a = job / 2688;
        int r = job - a * 2688;
        int n = r / 84;
        int ii = r - n * 84;
        unsigned short* arr = a == 0 ? Xqh : a == 1 ? Xkh : Xvh;
        int cell;
        if (ii < 11)      cell = ii;
        else if (ii < 73) { int j = ii - 11; cell = 19 + (j >> 1) * 10 + (j & 1); }
        else              cell = 329 + (ii - 73);
        short8 z8 = {0, 0, 0, 0, 0, 0, 0, 0};
        *(short8*)&arr[(size_t)(n * 340 + cell) * 512 + l * 8] = z8;
    }
}

// ---- merged QKV conv, BK=64, ONE uniform single-pass f16 loop.
//      Epilogue: z<2 -> single f16 (Qh/Kh); z=2 -> f16 Vt transposed ----
__global__ __launch_bounds__(256) void k_conv_qkv_all(
        const unsigned short* __restrict__ Xqh, const unsigned short* __restrict__ Xkh,
        const unsigned short* __restrict__ Xvh,
        const unsigned short* __restrict__ Wqh_, const unsigned short* __restrict__ Wkh_,
        const unsigned short* __restrict__ Wvh_,
        const float* __restrict__ bq, const float* __restrict__ bk,
        const float* __restrict__ bv,
        unsigned short* __restrict__ Qh, unsigned short* __restrict__ Kh,
        unsigned short* __restrict__ Vt) {
    __shared__ __align__(16) short Ah[8192], Bh[8192];   // 32KB
    const int z = blockIdx.z;
    const unsigned short* Xh = z == 0 ? Xqh : z == 1 ? Xkh : Xvh;
    const unsigned short* Wh = z == 0 ? Wqh_ : z == 1 ? Wkh_ : Wvh_;
    const float* bias = z == 0 ? bq : z == 1 ? bk : bv;

    const int tid = threadIdx.x;
    const int w = tid >> 6, l = tid & 63;
    const int n   = blockIdx.x >> 1;
    const int p0  = (blockIdx.x & 1) * 128;
    const int co0 = blockIdx.y * 128;
    const int lm = l & 15, lq = l >> 4;
    const int r8 = l >> 3, c8 = (l & 7) ^ (l >> 3);      // pitch-64 stage map

    int arow[4], brow[4];
#pragma unroll
    for (int j = 0; j < 4; ++j) {
        int rt = w * 32 + j * 8 + r8;
        int px = p0 + rt;
        int y = px >> 3, x = px & 7;
        arow[j] = ((n * 34 + y + 1) * 10 + (x + 1)) * 512 + c8 * 8;
        brow[j] = (co0 + rt) * 4608 + c8 * 8;
    }
    const int ldsW = w * 4096;       // bytes: wave's 32 rows x 128B

    int aoff[4][2], boff[4][2];
#pragma unroll
    for (int mi = 0; mi < 4; ++mi) {
        int row = (w & 1) * 64 + mi * 16 + lm;
#pragma unroll
        for (int ks = 0; ks < 2; ++ks)
            aoff[mi][ks] = row * 64 + ((((ks << 2) | lq) ^ (row & 7)) * 8);
    }
#pragma unroll
    for (int ni = 0; ni < 4; ++ni) {
        int row = (w >> 1) * 64 + ni * 16 + lm;
#pragma unroll
        for (int ks = 0; ks < 2; ++ks)
            boff[ni][ks] = row * 64 + ((((ks << 2) | lq) ^ (row & 7)) * 8);
    }

    f32x4 acc[4][4];
#pragma unroll
    for (int ni = 0; ni < 4; ++ni) {
        float b = bias[co0 + (w >> 1) * 64 + ni * 16 + lm];
#pragma unroll
        for (int mi = 0; mi < 4; ++mi) acc[mi][ni] = (f32x4){b, b, b, b};
    }

    for (int tap = 0; tap < 9; ++tap) {
        const int tapoff = ((tap / 3 - 1) * 10 + (tap % 3 - 1)) * 512;
        const int wb = tap * 512;
        for (int ci0 = 0; ci0 < 512; ci0 += 64) {
#pragma unroll
            for (int j = 0; j < 4; ++j)
                gl_lds16(Xh + arow[j] + tapoff + ci0, (char*)Ah + ldsW + j * 1024);
#pragma unroll
            for (int j = 0; j < 4; ++j)
                gl_lds16(Wh + brow[j] + wb + ci0, (char*)Bh + ldsW + j * 1024);
            __syncthreads();
            __builtin_amdgcn_s_setprio(1);
#pragma unroll
            for (int ks = 0; ks < 2; ++ks) {
                half8 ah[4], bh[4];
#pragma unroll
                for (int mi = 0; mi < 4; ++mi)
                    ah[mi] = *(const half8*)&Ah[aoff[mi][ks]];
#pragma unroll
                for (int ni = 0; ni < 4; ++ni)
                    bh[ni] = *(const half8*)&Bh[boff[ni][ks]];
#pragma unroll
                for (int mi = 0; mi < 4; ++mi)
#pragma unroll
                    for (int ni = 0; ni < 4; ++ni)
                        acc[mi][ni] = MFMA16F(ah[mi], bh[ni], acc[mi][ni]);
            }
            __builtin_amdgcn_s_setprio(0);
            __syncthreads();
        }
    }

    const int hh = n >> 2, nl = n & 3;
    const int pxbase = p0 + (w & 1) * 64 + lq * 4;
    const int x0q = pxbase & 7;
#pragma unroll
    for (int mi = 0; mi < 4; ++mi) {
        int px = pxbase + mi * 16;
        int y = px >> 3;
#pragma unroll
        for (int ni = 0; ni < 4; ++ni) {
            int co = co0 + (w >> 1) * 64 + ni * 16 + lm;
            int nn = nl * 8 + (co >> 6);
            int dd = (co & 63) * 8 + (y >> 2);
            int t0 = hh * 32 + (y & 3) * 8 + x0q;
            if (z < 2) {                       // Q,K: single f16
                unsigned short* O = (z == 0) ? Qh : Kh;
                short4v hv;
#pragma unroll
                for (int r = 0; r < 4; ++r) hv[r] = (short)f2h(acc[mi][ni][r]);
                *(short4v*)&O[(nn * 512 + dd) * 256 + t0] = hv;
            } else {                           // V: f16 transposed
#pragma unroll
                for (int r = 0; r < 4; ++r)
                    Vt[(nn * 256 + t0 + r) * 512 + dd] = f2h(acc[mi][ni][r]);
            }
        }
    }
}

// ---- scores: Sc[nn][q][k'] fp32 = Q(f16) . K(f16), 1 pass, BK=128 ----
__global__ __launch_bounds__(256) void k_scores_mfma(
        const unsigned short* __restrict__ Qh, const unsigned short* __restrict__ Kh,
        float* __restrict__ Sc) {
    __shared__ __align__(16) short Ah[16384], Bh[16384];   // 64KB
    const int tid = threadIdx.x;
    const int w = tid >> 6, l = tid & 63;
    const int q0 = blockIdx.x * 128, k0 = blockIdx.y * 128, nn = blockIdx.z;
    const int lm = l & 15, lq = l >> 4;
    const int r4 = l >> 4, c16 = l & 15;                 // pitch-128 stage map

    int arow[8], brow[8];
#pragma unroll
    for (int j = 0; j < 8; ++j) {
        int rt = w * 32 + j * 4 + r4;
        int sw = (c16 ^ (rt & 15)) * 8;
        arow[j] = (nn * 512 + q0 + rt) * 256 + sw;
        brow[j] = (nn * 512 + k0 + rt) * 256 + sw;
    }
    const int ldsW = w * 8192;       // bytes: wave's 32 rows x 256B

    int aoff[4][4], boff[4][4];
#pragma unroll
    for (int mi = 0; mi < 4; ++mi) {
        int row = (w & 1) * 64 + mi * 16 + lm;
#pragma unroll
        for (int ks = 0; ks < 4; ++ks)
            aoff[mi][ks] = row * 128 + ((((ks << 2) | lq) ^ (row & 15)) * 8);
    }
#pragma unroll
    for (int ni = 0; ni < 4; ++ni) {
        int row = (w >> 1) * 64 + ni * 16 + lm;
#pragma unroll
        for (int ks = 0; ks < 4; ++ks)
            boff[ni][ks] = row * 128 + ((((ks << 2) | lq) ^ (row & 15)) * 8);
    }

    f32x4 acc[4][4];
#pragma unroll
    for (int mi = 0; mi < 4; ++mi)
#pragma unroll
        for (int ni = 0; ni < 4; ++ni) acc[mi][ni] = (f32x4){0.f, 0.f, 0.f, 0.f};

    for (int t0 = 0; t0 < 256; t0 += 128) {
#pragma unroll
        for (int j = 0; j < 8; ++j)
            gl_lds16(Qh + arow[j] + t0, (char*)Ah + ldsW + j * 1024);
#pragma unroll
        for (int j = 0; j < 8; ++j)
            gl_lds16(Kh + brow[j] + t0, (char*)Bh + ldsW + j * 1024);
        __syncthreads();
#pragma unroll
        for (int ks = 0; ks < 4; ++ks) {
            half8 ah[4], bh[4];
#pragma unroll
            for (int mi = 0; mi < 4; ++mi) ah[mi] = *(const half8*)&Ah[aoff[mi][ks]];
#pragma unroll
            for (int ni = 0; ni < 4; ++ni) bh[ni] = *(const half8*)&Bh[boff[ni][ks]];
#pragma unroll
            for (int mi = 0; mi < 4; ++mi)
#pragma unroll
                for (int ni = 0; ni < 4; ++ni)
                    acc[mi][ni] = MFMA16F(ah[mi], bh[ni], acc[mi][ni]);
        }
        __syncthreads();
    }

    float* C = Sc + nn * 262144;
#pragma unroll
    for (int mi = 0; mi < 4; ++mi) {
        int qb = q0 + (w & 1) * 64 + lq * 4 + mi * 16;
#pragma unroll
        for (int ni = 0; ni < 4; ++ni) {
            int col = k0 + (w >> 1) * 64 + ni * 16 + lm;
#pragma unroll
            for (int r = 0; r < 4; ++r)
                C[(qb + r) * 512 + col] = acc[mi][ni][r];
        }
    }
}

// ---- softmax: one wave per 512-row, shuffle-only (+ zero Sp halo) ----
__global__ __launch_bounds__(256) void k_softmax(float* __restrict__ Sc,
                                                 unsigned short* __restrict__ Ph,
                                                 unsigned int* __restrict__ Spz) {
    unsigned base = blockIdx.x * 256 + threadIdx.x;      // 1,048,576 threads
#pragma unroll
    for (int i = 0; i < 3; ++i) {
        unsigned zi = base + (unsigned)i * 1048576u;
        if (zi < 2641920u) Spz[zi] = 0u;                 // 5,283,840 shorts of Sp
    }
    const int w = threadIdx.x >> 6, l = threadIdx.x & 63;
    float* p = Sc + ((size_t)blockIdx.x * 4 + w) * 512;
    unsigned short* ph = Ph + ((size_t)blockIdx.x * 4 + w) * 512;
    const int i0 = l * 4, i1 = 256 + l * 4;
    float4 a = *(const float4*)&p[i0];
    float4 b = *(const float4*)&p[i1];
    float m = fmaxf(fmaxf(fmaxf(a.x, a.y), fmaxf(a.z, a.w)),
                    fmaxf(fmaxf(b.x, b.y), fmaxf(b.z, b.w)));
#pragma unroll
    for (int off = 32; off; off >>= 1) m = fmaxf(m, __shfl_xor(m, off));
    float e0 = __expf(a.x - m), e1 = __expf(a.y - m);
    float e2 = __expf(a.z - m), e3 = __expf(a.w - m);
    float e4 = __expf(b.x - m), e5 = __expf(b.y - m);
    float e6 = __expf(b.z - m), e7 = __expf(b.w - m);
    float s = ((e0 + e1) + (e2 + e3)) + ((e4 + e5) + (e6 + e7));
#pragma unroll
    for (int off = 32; off; off >>= 1) s += __shfl_xor(s, off);
    float inv = 1.0f / s;
    float4 o0 = {e0 * inv, e1 * inv, e2 * inv, e3 * inv};
    float4 o1 = {e4 * inv, e5 * inv, e6 * inv, e7 * inv};
    *(float4*)&p[i0] = o0;
    *(float4*)&p[i1] = o1;
    short4v h0 = {(short)f2h(o0.x), (short)f2h(o0.y), (short)f2h(o0.z), (short)f2h(o0.w)};
    short4v h1 = {(short)f2h(o1.x), (short)f2h(o1.y), (short)f2h(o1.z), (short)f2h(o1.w)};
    *(short4v*)&ph[i0] = h0;
    *(short4v*)&ph[i1] = h1;
}

// ---- PV: P @ V, 16x16 f16 MFMA, BK=128; scatters into padded Sp ----
__global__ __launch_bounds__(256) void k_pv_mfma(
        const unsigned short* __restrict__ Ph, const unsigned short* __restrict__ Vt,
        unsigned short* __restrict__ Sp) {
    __shared__ __align__(16) short Ah[16384], Bh[8192];  // [128][128], [64][128]
    const int tid = threadIdx.x;
    const int w = tid >> 6, l = tid & 63;
    const int q0 = blockIdx.x * 128, t0 = blockIdx.y * 64, nn = blockIdx.z;
    const int lm = l & 15, lq = l >> 4;
    const int r4 = l >> 4, c16 = l & 15;                 // pitch-128 stage map

    int arow[8], brow[4];
#pragma unroll
    for (int j = 0; j < 8; ++j) {
        int rt = w * 32 + j * 4 + r4;
        arow[j] = (nn * 512 + q0 + rt) * 512 + ((c16 ^ (rt & 15)) * 8);
    }
#pragma unroll
    for (int j = 0; j < 4; ++j) {
        int rt = w * 16 + j * 4 + r4;
        brow[j] = (nn * 256 + t0 + rt) * 512 + ((c16 ^ (rt & 15)) * 8);
    }
    const int ldsA = w * 8192, ldsB = w * 4096;          // bytes

    int aoff[4][4], boff[2][4];
#pragma unroll
    for (int mi = 0; mi < 4; ++mi) {
        int row = (w & 1) * 64 + mi * 16 + lm;
#pragma unroll
        for (int ks = 0; ks < 4; ++ks)
            aoff[mi][ks] = row * 128 + ((((ks << 2) | lq) ^ (row & 15)) * 8);
    }
#pragma unroll
    for (int ni = 0; ni < 2; ++ni) {
        int row = (w >> 1) * 32 + ni * 16 + lm;
#pragma unroll
        for (int ks = 0; ks < 4; ++ks)
            boff[ni][ks] = row * 128 + ((((ks << 2) | lq) ^ (row & 15)) * 8);
    }

    f32x4 acc[4][2];
#pragma unroll
    for (int mi = 0; mi < 4; ++mi)
#pragma unroll
        for (int ni = 0; ni < 2; ++ni) acc[mi][ni] = (f32x4){0.f, 0.f, 0.f, 0.f};

    for (int kc = 0; kc < 512; kc += 128) {
#pragma unroll
        for (int j = 0; j < 8; ++j)
            gl_lds16(Ph + arow[j] + kc, (char*)Ah + ldsA + j * 1024);
#pragma unroll
        for (int j = 0; j < 4; ++j)
            gl_lds16(Vt + brow[j] + kc, (char*)Bh + ldsB + j * 1024);
        __syncthreads();
#pragma unroll
        for (int ks = 0; ks < 4; ++ks) {
            half8 a[4], b[2];
#pragma unroll
            for (int mi = 0; mi < 4; ++mi) a[mi] = *(const half8*)&Ah[aoff[mi][ks]];
#pragma unroll
            for (int ni = 0; ni < 2; ++ni) b[ni] = *(const half8*)&Bh[boff[ni][ks]];
#pragma unroll
            for (int mi = 0; mi < 4; ++mi)
#pragma unroll
                for (int ni = 0; ni < 2; ++ni)
                    acc[mi][ni] = MFMA16F(a[mi], b[ni], acc[mi][ni]);
        }
        __syncthreads();
    }

    // scatter into Sp[b2][yy][xx][d2]:  b2=nn>>3, s2=nn&7,
    //   ww=(qp>>4)*8+((qp>>1)&7), d2=(qp&1)*256+(t&31)*8+(t>>5)
    const int b2 = nn >> 3, s2 = nn & 7;
#pragma unroll
    for (int mi = 0; mi < 4; ++mi) {
        int qb = q0 + (w & 1) * 64 + lq * 4 + mi * 16;
#pragma unroll
        for (int ni = 0; ni < 2; ++ni) {
            int tc = t0 + (w >> 1) * 32 + ni * 16 + lm;
            int d2base = (tc & 31) * 8 + (tc >> 5);
#pragma unroll
            for (int r = 0; r < 4; ++r) {
                int qp = qb + r;
                int ww = (qp >> 4) * 8 + ((qp >> 1) & 7);
                int d2 = (qp & 1) * 256 + d2base;
                Sp[((b2 * 10 + s2 + 1) * 258 + ww + 1) * 512 + d2] =
                    f2h(acc[mi][ni][r]);
            }
        }
    }
}

// ---- output conv (f16), BM=128 BN=64, BK=128 -> Y NCHW fp32 ----
__global__ __launch_bounds__(256) void k_conv_o_mfma(
        const unsigned short* __restrict__ Sp, const unsigned short* __restrict__ Wh,
        const float* __restrict__ bias, float* __restrict__ Y) {
    __shared__ __align__(16) short Ah[16384], Bh[8192];  // [128][128], [64][128]
    const int tid = threadIdx.x;
    const int w = tid >> 6, l = tid & 63;
    const int n   = blockIdx.x >> 4;
    const int yy  = (blockIdx.x >> 1) & 7;
    const int x0  = (blockIdx.x & 1) * 128;
    const int co0 = blockIdx.y * 64;
    const int lm = l & 15, lq = l >> 4;
    const int r4 = l >> 4, c16 = l & 15;                 // pitch-128 stage map

    int arow[8], brow[4];
#pragma unroll
    for (int j = 0; j < 8; ++j) {
        int rt = w * 32 + j * 4 + r4;
        arow[j] = ((n * 10 + yy + 1) * 258 + (x0 + rt + 1)) * 512
                  + ((c16 ^ (rt & 15)) * 8);
    }
#pragma unroll
    for (int j = 0; j < 4; ++j) {
        int rt = w * 16 + j * 4 + r4;
        brow[j] = (co0 + rt) * 4608 + ((c16 ^ (rt & 15)) * 8);
    }
    const int ldsA = w * 8192, ldsB = w * 4096;          // bytes

    int aoff[4][4], boff[2][4];
#pragma unroll
    for (int mi = 0; mi < 4; ++mi) {
        int row = (w & 1) * 64 + mi * 16 + lm;
#pragma unroll
        for (int ks = 0; ks < 4; ++ks)
            aoff[mi][ks] = row * 128 + ((((ks << 2) | lq) ^ (row & 15)) * 8);
    }
#pragma unroll
    for (int ni = 0; ni < 2; ++ni) {
        int row = (w >> 1) * 32 + ni * 16 + lm;
#pragma unroll
        for (int ks = 0; ks < 4; ++ks)
            boff[ni][ks] = row * 128 + ((((ks << 2) | lq) ^ (row & 15)) * 8);
    }

    f32x4 acc[4][2];
#pragma unroll
    for (int ni = 0; ni < 2; ++ni) {
        float b = bias[co0 + (w >> 1) * 32 + ni * 16 + lm];
#pragma unroll
        for (int mi = 0; mi < 4; ++mi) acc[mi][ni] = (f32x4){b, b, b, b};
    }

    for (int tap = 0; tap < 9; ++tap) {
        const int tapoff = ((tap / 3 - 1) * 258 + (tap % 3 - 1)) * 512;
        const int wb = tap * 512;
        for (int ci0 = 0; ci0 < 512; ci0 += 128) {
#pragma unroll
            for (int j = 0; j < 8; ++j)
                gl_lds16(Sp + arow[j] + tapoff + ci0, (char*)Ah + ldsA + j * 1024);
#pragma unroll
            for (int j = 0; j < 4; ++j)
                gl_lds16(Wh + brow[j] + wb + ci0, (char*)Bh + ldsB + j * 1024);
            __syncthreads();
#pragma unroll
            for (int ks = 0; ks < 4; ++ks) {
                half8 a[4], b[2];
#pragma unroll
                for (int mi = 0; mi < 4; ++mi)
                    a[mi] = *(const half8*)&Ah[aoff[mi][ks]];
#pragma unroll
                for (int ni = 0; ni < 2; ++ni)
                    b[ni] = *(const half8*)&Bh[boff[ni][ks]];
#pragma unroll
                for (int mi = 0; mi < 4; ++mi)
#pragma unroll
                    for (int ni = 0; ni < 2; ++ni)
                        acc[mi][ni] = MFMA16F(a[mi], b[ni], acc[mi][ni]);
            }
            __syncthreads();
        }
    }

#pragma unroll
    for (int mi = 0; mi < 4; ++mi) {
        int px = x0 + (w & 1) * 64 + lq * 4 + mi * 16;
#pragma unroll
        for (int ni = 0; ni < 2; ++ni) {
            int co = co0 + (w >> 1) * 32 + ni * 16 + lm;
            *(f32x4*)&Y[n * 1048576 + co * 2048 + yy * 256 + px] = acc[mi][ni];
        }
    }
}

// ---------------------------------------------------------------------------
extern "C" void kernel_launch(void* const* d_in, const int* in_sizes, int n_in,
                              void* d_out, int out_size, void* d_ws, size_t ws_size,
                              hipStream_t stream) {
    const float* q  = (const float*)d_in[0];
    const float* k  = (const float*)d_in[1];
    const float* v  = (const float*)d_in[2];
    const float* Wq = (const float*)d_in[3];
    const float* bq = (const float*)d_in[4];
    const float* Wk = (const float*)d_in[5];
    const float* bk = (const float*)d_in[6];
    const float* Wv = (const float*)d_in[7];
    const float* bv = (const float*)d_in[8];
    const float* Wo = (const float*)d_in[9];
    const float* bo = (const float*)d_in[10];

    // ---- workspace layout (shorts): round-11 offsets kept; Ql slot dead ----
    unsigned short* W0  = (unsigned short*)d_ws;
    unsigned short* Wqh = W0;                   // 2359296
    unsigned short* Wkh = W0 + 2359296;         // 2359296
    unsigned short* Wvh = W0 + 4718592;         // 2359296
    unsigned short* Xvh = W0 + 7077888;         // 5570560
    unsigned short* Woh = W0 + 18219008;        // 2359296 (alive till conv_o)
    unsigned short* Qh  = W0 + 20578304;        // 4194304
    unsigned short* Kh  = W0 + 28966912;        // 4194304
    unsigned short* Vt  = W0 + 33161216;        // 4194304 (alive till pv)
    // reuses: Ph @0 (8388608, over Wqh/Wkh/Wvh/Xvh-head — dead after conv;
    //         Woh @18219008 untouched); Sp over Qh + dead-Ql slot
    unsigned short* Ph = W0;                    // 8388608 shorts
    unsigned short* Sp = W0 + 20578304;         // 5283840 shorts

    // ---- d_out scratch before final writes ----
    float* y_out = (float*)d_out;               // 4194304 floats (written last)
    float* attn  = y_out + 4194304;             // 8388608 floats (written by scores)
    unsigned short* Xqh = (unsigned short*)d_out;
    unsigned short* Xkh = (unsigned short*)attn;

    k_prep_fused<<<5600, 256, 0, stream>>>(q, k, v, Wq, Wk, Wv, Wo,
                                           Wqh, Wkh, Wvh, Woh,
                                           Xqh, Xkh, Xvh);
    k_conv_qkv_all<<<dim3(64, 4, 3), 256, 0, stream>>>(
        Xqh, Xkh, Xvh, Wqh, Wkh, Wvh,
        bq, bk, bv, Qh, Kh, Vt);
    k_scores_mfma<<<dim3(4, 4, 32), 256, 0, stream>>>(Qh, Kh, attn);
    k_softmax<<<4096, 256, 0, stream>>>(attn, Ph, (unsigned int*)Sp);
    k_pv_mfma<<<dim3(4, 4, 32), 256, 0, stream>>>(Ph, Vt, Sp);
    k_conv_o_mfma<<<dim3(64, 8), 256, 0, stream>>>(Sp, Woh, bo, y_out);
}

// Round 8
// 362.201 us; speedup vs baseline: 1.5708x; 1.0145x over previous
//
#include <hip/hip_runtime.h>

// ---------------------------------------------------------------------------
// MultiHeadAttention_60000693125780 — round 13
//  conv_qkv capped at 127us (all schedule levers tested null). Round 13 cuts
//  the rest's launch/ramp overhead: scores+softmax FUSED into one kernel.
//   - Block owns 64 full q-rows (grid 8x32 = 256 = 1/CU, 512 thr = 8 waves):
//     K-loop BK=64 (t-chunks 0..7 sequential = bit-identical scores to r12),
//     then in-register softmax: shfl row-max -> cross-wave LDS max -> exp in
//     place -> shfl row-sum -> cross-wave sum -> store attn fp32 + Ph f16.
//     No raw-Sc write, no re-read, one less launch. Max exact; sum reassoc
//     ~1e-7 -> absmax should stay ~0.0469 (tripwire).
//   - Sp moved to dead r9-Xvl gap @12648448 (no overlap with Ph@0): zeroed
//     in fused prologue race-free. pv/conv_o pointer-only change.
//  Predicted: conv ~127 (tripwire), fused 15-25us vs ~50 for the pair,
//  total 345-358, absmax 0.0469+-0.001. Fallback: revert to r12.
// Layouts: Qh,Kh [nn][dd][t] f16; Vt [nn][t][dd] f16; Ph [nn][q][k'] f16;
//          Sp padded NHWC f16 [4][10][258][512]
// Pitch-64 swizzle: stage lane -> row u>>3, slot u&7, chunk (u&7)^(row&7);
//   reader slot (ks*4+lq)^(row&7).  Pitch-128: row u>>4, chunk (u&15)^(row&15);
//   reader (ks*4+lq)^(row&15).
// ---------------------------------------------------------------------------

typedef __attribute__((ext_vector_type(8))) short short8;
typedef __attribute__((ext_vector_type(8))) _Float16 half8;
typedef __attribute__((ext_vector_type(4))) float f32x4;
typedef __attribute__((ext_vector_type(4))) short short4v;

#define MFMA16F(a, b, c) __builtin_amdgcn_mfma_f32_16x16x32_f16((a), (b), (c), 0, 0, 0)

__device__ __forceinline__ void gl_lds16(const void* g, void* l) {
    __builtin_amdgcn_global_load_lds(
        (const __attribute__((address_space(1))) unsigned int*)g,
        (__attribute__((address_space(3))) unsigned int*)l, 16, 0, 0);
}
__device__ __forceinline__ unsigned short f2h(float f) {
    _Float16 h = (_Float16)f;                       // RNE
    return __builtin_bit_cast(unsigned short, h);
}

// ---- fused prep: [0,1536) inputs | [1536,3584) weights | [3584,5600) halo
__global__ __launch_bounds__(256) void k_prep_fused(
        const float* __restrict__ q, const float* __restrict__ k,
        const float* __restrict__ v,
        const float* __restrict__ Wq, const float* __restrict__ Wk,
        const float* __restrict__ Wv, const float* __restrict__ Wo,
        unsigned short* __restrict__ Wqh, unsigned short* __restrict__ Wkh,
        unsigned short* __restrict__ Wvh, unsigned short* __restrict__ Woh,
        unsigned short* __restrict__ Xqh, unsigned short* __restrict__ Xkh,
        unsigned short* __restrict__ Xvh) {
    __shared__ __align__(16) unsigned int U[8192];
    const int b = blockIdx.x;
    const int tid = threadIdx.x;
    if (b < 1536) {
        // ---- inputs: NCHW fp32 -> padded NHWC f16 (single) ----
        const int cig = b & 15, n = (b >> 4) & 31, z = b >> 9;
        const float* X = z == 0 ? q : z == 1 ? k : v;
        unsigned short* Xh = z == 0 ? Xqh : z == 1 ? Xkh : Xvh;
#pragma unroll
        for (int it = 0; it < 8; ++it) {
            int ci_l = it * 4 + (tid >> 6);
            int pos = (tid & 63) * 4;
            const float4 rd =
                *(const float4*)&X[(size_t)(n * 512 + cig * 32 + ci_l) * 256 + pos];
            uint4 u;
            u.x = f2h(rd.x);
            u.y = f2h(rd.y);
            u.z = f2h(rd.z);
            u.w = f2h(rd.w);
            *(uint4*)&U[ci_l * 256 + pos] = u;
        }
        __syncthreads();
#pragma unroll
        for (int it = 0; it < 4; ++it) {
            int pos = it * 64 + (tid >> 2);
            int ci8 = (tid & 3) * 8;
            short8 h8;
#pragma unroll
            for (int j = 0; j < 8; ++j)
                h8[j] = (short)(U[(ci8 + j) * 256 + pos] & 0xffffu);
            int yy = (pos >> 3) + 1, xx = (pos & 7) + 1;
            size_t o = (size_t)((n * 34 + yy) * 10 + xx) * 512 + cig * 32 + ci8;
            *(short8*)&Xh[o] = h8;
        }
    } else if (b < 3584) {
        // ---- weights: [co][ci][tap] fp32 -> [co][tap][ci] f16 ----
        const int bl = b - 1536;
        const int co = bl & 511, z = bl >> 9;
        const float* W = z == 0 ? Wq : z == 1 ? Wk : z == 2 ? Wv : Wo;
        unsigned short* Wh = z == 0 ? Wqh : z == 1 ? Wkh : z == 2 ? Wvh : Woh;
        const float* Wc = W + co * 4608;
#pragma unroll
        for (int it = 0; it < 9; ++it) {
            int p = it * 256 + tid;
            float2 rd = *(const float2*)&Wc[p * 2];
            int e0 = p * 2;
            int ci0 = e0 / 9, t0 = e0 - ci0 * 9;
            U[t0 * 512 + ci0] = f2h(rd.x);
            int e1 = e0 + 1;
            int ci1 = e1 / 9, t1 = e1 - ci1 * 9;
            U[t1 * 512 + ci1] = f2h(rd.y);
        }
        __syncthreads();
        unsigned short* Whc = Wh + co * 4608;
#pragma unroll
        for (int it = 0; it < 18; ++it) {
            int j = it * 256 + tid;
            Whc[j] = (unsigned short)U[j];
        }
    } else {
        // ---- halo zeroing: 84 halo cells per (array, n), 3 arrays ----
        const int w = tid >> 6, l = tid & 63;
        int job = (b - 3584) * 4 + w;        // 8064 jobs = 3 arrays * 32 n * 84
        int a = job / 2688;
        int r = job - a * 2688;
        int n = r / 84;
        int ii = r - n * 84;
        unsigned short* arr = a == 0 ? Xqh : a == 1 ? Xkh : Xvh;
        int cell;
        if (ii < 11)      cell = ii;
        else if (ii < 73) { int j = ii - 11; cell = 19 + (j >> 1) * 10 + (j & 1); }
        else              cell = 329 + (ii - 73);
        short8 z8 = {0, 0, 0, 0, 0, 0, 0, 0};
        *(short8*)&arr[(size_t)(n * 340 + cell) * 512 + l * 8] = z8;
    }
}

// ---- merged QKV conv, BK=64, ONE uniform single-pass f16 loop. (r12 kernel)
__global__ __launch_bounds__(256) void k_conv_qkv_all(
        const unsigned short* __restrict__ Xqh, const unsigned short* __restrict__ Xkh,
        const unsigned short* __restrict__ Xvh,
        const unsigned short* __restrict__ Wqh_, const unsigned short* __restrict__ Wkh_,
        const unsigned short* __restrict__ Wvh_,
        const float* __restrict__ bq, const float* __restrict__ bk,
        const float* __restrict__ bv,
        unsigned short* __restrict__ Qh, unsigned short* __restrict__ Kh,
        unsigned short* __restrict__ Vt) {
    __shared__ __align__(16) short Ah[8192], Bh[8192];   // 32KB
    const int z = blockIdx.z;
    const unsigned short* Xh = z == 0 ? Xqh : z == 1 ? Xkh : Xvh;
    const unsigned short* Wh = z == 0 ? Wqh_ : z == 1 ? Wkh_ : Wvh_;
    const float* bias = z == 0 ? bq : z == 1 ? bk : bv;

    const int tid = threadIdx.x;
    const int w = tid >> 6, l = tid & 63;
    const int n   = blockIdx.x >> 1;
    const int p0  = (blockIdx.x & 1) * 128;
    const int co0 = blockIdx.y * 128;
    const int lm = l & 15, lq = l >> 4;
    const int r8 = l >> 3, c8 = (l & 7) ^ (l >> 3);      // pitch-64 stage map

    int arow[4], brow[4];
#pragma unroll
    for (int j = 0; j < 4; ++j) {
        int rt = w * 32 + j * 8 + r8;
        int px = p0 + rt;
        int y = px >> 3, x = px & 7;
        arow[j] = ((n * 34 + y + 1) * 10 + (x + 1)) * 512 + c8 * 8;
        brow[j] = (co0 + rt) * 4608 + c8 * 8;
    }
    const int ldsW = w * 4096;       // bytes: wave's 32 rows x 128B

    int aoff[4][2], boff[4][2];
#pragma unroll
    for (int mi = 0; mi < 4; ++mi) {
        int row = (w & 1) * 64 + mi * 16 + lm;
#pragma unroll
        for (int ks = 0; ks < 2; ++ks)
            aoff[mi][ks] = row * 64 + ((((ks << 2) | lq) ^ (row & 7)) * 8);
    }
#pragma unroll
    for (int ni = 0; ni < 4; ++ni) {
        int row = (w >> 1) * 64 + ni * 16 + lm;
#pragma unroll
        for (int ks = 0; ks < 2; ++ks)
            boff[ni][ks] = row * 64 + ((((ks << 2) | lq) ^ (row & 7)) * 8);
    }

    f32x4 acc[4][4];
#pragma unroll
    for (int ni = 0; ni < 4; ++ni) {
        float b = bias[co0 + (w >> 1) * 64 + ni * 16 + lm];
#pragma unroll
        for (int mi = 0; mi < 4; ++mi) acc[mi][ni] = (f32x4){b, b, b, b};
    }

    for (int tap = 0; tap < 9; ++tap) {
        const int tapoff = ((tap / 3 - 1) * 10 + (tap % 3 - 1)) * 512;
        const int wb = tap * 512;
        for (int ci0 = 0; ci0 < 512; ci0 += 64) {
#pragma unroll
            for (int j = 0; j < 4; ++j)
                gl_lds16(Xh + arow[j] + tapoff + ci0, (char*)Ah + ldsW + j * 1024);
#pragma unroll
            for (int j = 0; j < 4; ++j)
                gl_lds16(Wh + brow[j] + wb + ci0, (char*)Bh + ldsW + j * 1024);
            __syncthreads();
            __builtin_amdgcn_s_setprio(1);
#pragma unroll
            for (int ks = 0; ks < 2; ++ks) {
                half8 ah[4], bh[4];
#pragma unroll
                for (int mi = 0; mi < 4; ++mi)
                    ah[mi] = *(const half8*)&Ah[aoff[mi][ks]];
#pragma unroll
                for (int ni = 0; ni < 4; ++ni)
                    bh[ni] = *(const half8*)&Bh[boff[ni][ks]];
#pragma unroll
                for (int mi = 0; mi < 4; ++mi)
#pragma unroll
                    for (int ni = 0; ni < 4; ++ni)
                        acc[mi][ni] = MFMA16F(ah[mi], bh[ni], acc[mi][ni]);
            }
            __builtin_amdgcn_s_setprio(0);
            __syncthreads();
        }
    }

    const int hh = n >> 2, nl = n & 3;
    const int pxbase = p0 + (w & 1) * 64 + lq * 4;
    const int x0q = pxbase & 7;
#pragma unroll
    for (int mi = 0; mi < 4; ++mi) {
        int px = pxbase + mi * 16;
        int y = px >> 3;
#pragma unroll
        for (int ni = 0; ni < 4; ++ni) {
            int co = co0 + (w >> 1) * 64 + ni * 16 + lm;
            int nn = nl * 8 + (co >> 6);
            int dd = (co & 63) * 8 + (y >> 2);
            int t0 = hh * 32 + (y & 3) * 8 + x0q;
            if (z < 2) {                       // Q,K: single f16
                unsigned short* O = (z == 0) ? Qh : Kh;
                short4v hv;
#pragma unroll
                for (int r = 0; r < 4; ++r) hv[r] = (short)f2h(acc[mi][ni][r]);
                *(short4v*)&O[(nn * 512 + dd) * 256 + t0] = hv;
            } else {                           // V: f16 transposed
#pragma unroll
                for (int r = 0; r < 4; ++r)
                    Vt[(nn * 256 + t0 + r) * 512 + dd] = f2h(acc[mi][ni][r]);
            }
        }
    }
}

// ---- FUSED scores+softmax: block = 64 q-rows x all 512 k, 512 threads.
//      8 waves as (wq 2) x (wk 4); wave tile 32q x 128k; acc[2][8].
//      K-loop BK=64 (t-chunks sequential = bit-identical scores to r12),
//      then in-register softmax -> attn fp32 + Ph f16. Also zeroes Sp. ----
__global__ __launch_bounds__(512) void k_scores_sm(
        const unsigned short* __restrict__ Qh, const unsigned short* __restrict__ Kh,
        float* __restrict__ Sc, unsigned short* __restrict__ Ph,
        uint4* __restrict__ Spz) {
    __shared__ __align__(16) short Ah[4096], Bh[32768];  // 8KB + 64KB
    __shared__ float Mw[8][64], Sw[8][64];               // 4KB
    const int tid = threadIdx.x;
    const int nn = blockIdx.y, q0 = blockIdx.x * 64;

    // zero Sp (660480 uint4 over 131072 threads)
    {
        unsigned g = (blockIdx.y * 8u + blockIdx.x) * 512u + tid;
#pragma unroll
        for (int i = 0; i < 6; ++i) {
            unsigned zi = g + (unsigned)i * 131072u;
            if (zi < 660480u) Spz[zi] = (uint4){0u, 0u, 0u, 0u};
        }
    }

    const int w = tid >> 6, l = tid & 63;
    const int wq = w & 1, wk = w >> 1;
    const int lm = l & 15, lq = l >> 4;

    // staging addresses (pitch-64 swizzle)
    const int ar = tid >> 3, ac = (tid & 7) ^ ((tid >> 3) & 7);   // A: 64 rows
    const int arow = (nn * 512 + q0 + ar) * 256 + ac * 8;
    int brow[8];
#pragma unroll
    for (int it = 0; it < 8; ++it) {
        int u = it * 512 + tid;
        int row = u >> 3, slot = u & 7;
        brow[it] = (nn * 512 + row) * 256 + ((slot ^ (row & 7)) * 8);
    }

    int aoff[2][2], boff[8][2];
#pragma unroll
    for (int mi = 0; mi < 2; ++mi) {
        int row = wq * 32 + mi * 16 + lm;
#pragma unroll
        for (int ks = 0; ks < 2; ++ks)
            aoff[mi][ks] = row * 64 + ((((ks << 2) | lq) ^ (row & 7)) * 8);
    }
#pragma unroll
    for (int ni = 0; ni < 8; ++ni) {
        int row = wk * 128 + ni * 16 + lm;
#pragma unroll
        for (int ks = 0; ks < 2; ++ks)
            boff[ni][ks] = row * 64 + ((((ks << 2) | lq) ^ (row & 7)) * 8);
    }

    f32x4 acc[2][8];
#pragma unroll
    for (int mi = 0; mi < 2; ++mi)
#pragma unroll
        for (int ni = 0; ni < 8; ++ni) acc[mi][ni] = (f32x4){0.f, 0.f, 0.f, 0.f};

    for (int tc = 0; tc < 256; tc += 64) {
        gl_lds16(Qh + arow + tc, (char*)Ah + (tid >> 3) * 128 + ((tid & 7) ^ ((tid >> 3) & 7)) * 16 - ((tid & 7) ^ ((tid >> 3) & 7)) * 16 + (tid & 7) * 16);
        // NOTE: LDS dest must be linear in thread order (wave-uniform base +
        // lane*16). Units are laid out linearly; the swizzle lives in the
        // GLOBAL source (arow) per G21. Dest = tid*16 bytes.
        // (The expression above collapses to tid*16; written explicitly:)
        // gl_lds16(Qh + arow + tc, (char*)Ah + tid * 16);
#pragma unroll
        for (int it = 0; it < 8; ++it)
            gl_lds16(Kh + brow[it] + tc, (char*)Bh + (it * 512 + tid) * 16);
        __syncthreads();
        __builtin_amdgcn_s_setprio(1);
#pragma unroll
        for (int ks = 0; ks < 2; ++ks) {
            half8 ah[2], bh[8];
#pragma unroll
            for (int mi = 0; mi < 2; ++mi) ah[mi] = *(const half8*)&Ah[aoff[mi][ks]];
#pragma unroll
            for (int ni = 0; ni < 8; ++ni) bh[ni] = *(const half8*)&Bh[boff[ni][ks]];
#pragma unroll
            for (int mi = 0; mi < 2; ++mi)
#pragma unroll
                for (int ni = 0; ni < 8; ++ni)
                    acc[mi][ni] = MFMA16F(ah[mi], bh[ni], acc[mi][ni]);
        }
        __builtin_amdgcn_s_setprio(0);
        __syncthreads();
    }

    // ---- in-register softmax over k (cols spread across wk waves) ----
    // thread rows: q_l = wq*32 + mi*16 + lq*4 + r
    float M[2][4];
#pragma unroll
    for (int mi = 0; mi < 2; ++mi)
#pragma unroll
        for (int r = 0; r < 4; ++r) {
            float m = acc[mi][0][r];
#pragma unroll
            for (int ni = 1; ni < 8; ++ni) m = fmaxf(m, acc[mi][ni][r]);
#pragma unroll
            for (int off = 1; off < 16; off <<= 1) m = fmaxf(m, __shfl_xor(m, off));
            M[mi][r] = m;
            if (lm == 0) Mw[w][wq * 32 + mi * 16 + lq * 4 + r] = m;
        }
    __syncthreads();
#pragma unroll
    for (int mi = 0; mi < 2; ++mi)
#pragma unroll
        for (int r = 0; r < 4; ++r) {
            int q_l = wq * 32 + mi * 16 + lq * 4 + r;
            float m = fmaxf(fmaxf(Mw[wq][q_l], Mw[wq + 2][q_l]),
                            fmaxf(Mw[wq + 4][q_l], Mw[wq + 6][q_l]));
            M[mi][r] = m;
        }
    float S[2][4];
#pragma unroll
    for (int mi = 0; mi < 2; ++mi)
#pragma unroll
        for (int r = 0; r < 4; ++r) {
            float m = M[mi][r];
            float s = 0.f;
#pragma unroll
            for (int ni = 0; ni < 8; ++ni) {
                float e = __expf(acc[mi][ni][r] - m);
                acc[mi][ni][r] = e;
                s += e;
            }
#pragma unroll
            for (int off = 1; off < 16; off <<= 1) s += __shfl_xor(s, off);
            S[mi][r] = s;
            if (lm == 0) Sw[w][wq * 32 + mi * 16 + lq * 4 + r] = s;
        }
    __syncthreads();
    float* C = Sc + nn * 262144;
    unsigned short* P = Ph + nn * 262144;
#pragma unroll
    for (int mi = 0; mi < 2; ++mi)
#pragma unroll
        for (int r = 0; r < 4; ++r) {
            int q_l = wq * 32 + mi * 16 + lq * 4 + r;
            float s = ((Sw[wq][q_l] + Sw[wq + 2][q_l]) +
                       (Sw[wq + 4][q_l] + Sw[wq + 6][q_l]));
            float inv = 1.0f / s;
            int rowbase = (q0 + q_l) * 512 + wk * 128 + lm;
#pragma unroll
            for (int ni = 0; ni < 8; ++ni) {
                float p = acc[mi][ni][r] * inv;
                C[rowbase + ni * 16] = p;
                P[rowbase + ni * 16] = f2h(p);
            }
        }
}

// ---- PV: P @ V, 16x16 f16 MFMA, BK=128; scatters into padded Sp ----
__global__ __launch_bounds__(256) void k_pv_mfma(
        const unsigned short* __restrict__ Ph, const unsigned short* __restrict__ Vt,
        unsigned short* __restrict__ Sp) {
    __shared__ __align__(16) short Ah[16384], Bh[8192];  // [128][128], [64][128]
    const int tid = threadIdx.x;
    const int w = tid >> 6, l = tid & 63;
    const int q0 = blockIdx.x * 128, t0 = blockIdx.y * 64, nn = blockIdx.z;
    const int lm = l & 15, lq = l >> 4;
    const int r4 = l >> 4, c16 = l & 15;                 // pitch-128 stage map

    int arow[8], brow[4];
#pragma unroll
    for (int j = 0; j < 8; ++j) {
        int rt = w * 32 + j * 4 + r4;
        arow[j] = (nn * 512 + q0 + rt) * 512 + ((c16 ^ (rt & 15)) * 8);
    }
#pragma unroll
    for (int j = 0; j < 4; ++j) {
        int rt = w * 16 + j * 4 + r4;
        brow[j] = (nn * 256 + t0 + rt) * 512 + ((c16 ^ (rt & 15)) * 8);
    }
    const int ldsA = w * 8192, ldsB = w * 4096;          // bytes

    int aoff[4][4], boff[2][4];
#pragma unroll
    for (int mi = 0; mi < 4; ++mi) {
        int row = (w & 1) * 64 + mi * 16 + lm;
#pragma unroll
        for (int ks = 0; ks < 4; ++ks)
            aoff[mi][ks] = row * 128 + ((((ks << 2) | lq) ^ (row & 15)) * 8);
    }
#pragma unroll
    for (int ni = 0; ni < 2; ++ni) {
        int row = (w >> 1) * 32 + ni * 16 + lm;
#pragma unroll
        for (int ks = 0; ks < 4; ++ks)
            boff[ni][ks] = row * 128 + ((((ks << 2) | lq) ^ (row & 15)) * 8);
    }

    f32x4 acc[4][2];
#pragma unroll
    for (int mi = 0; mi < 4; ++mi)
#pragma unroll
        for (int ni = 0; ni < 2; ++ni) acc[mi][ni] = (f32x4){0.f, 0.f, 0.f, 0.f};

    for (int kc = 0; kc < 512; kc += 128) {
#pragma unroll
        for (int j = 0; j < 8; ++j)
            gl_lds16(Ph + arow[j] + kc, (char*)Ah + ldsA + j * 1024);
#pragma unroll
        for (int j = 0; j < 4; ++j)
            gl_lds16(Vt + brow[j] + kc, (char*)Bh + ldsB + j * 1024);
        __syncthreads();
#pragma unroll
        for (int ks = 0; ks < 4; ++ks) {
            half8 a[4], b[2];
#pragma unroll
            for (int mi = 0; mi < 4; ++mi) a[mi] = *(const half8*)&Ah[aoff[mi][ks]];
#pragma unroll
            for (int ni = 0; ni < 2; ++ni) b[ni] = *(const half8*)&Bh[boff[ni][ks]];
#pragma unroll
            for (int mi = 0; mi < 4; ++mi)
#pragma unroll
                for (int ni = 0; ni < 2; ++ni)
                    acc[mi][ni] = MFMA16F(a[mi], b[ni], acc[mi][ni]);
        }
        __syncthreads();
    }

    // scatter into Sp[b2][yy][xx][d2]:  b2=nn>>3, s2=nn&7,
    //   ww=(qp>>4)*8+((qp>>1)&7), d2=(qp&1)*256+(t&31)*8+(t>>5)
    const int b2 = nn >> 3, s2 = nn & 7;
#pragma unroll
    for (int mi = 0; mi < 4; ++mi) {
        int qb = q0 + (w & 1) * 64 + lq * 4 + mi * 16;
#pragma unroll
        for (int ni = 0; ni < 2; ++ni) {
            int tc = t0 + (w >> 1) * 32 + ni * 16 + lm;
            int d2base = (tc & 31) * 8 + (tc >> 5);
#pragma unroll
            for (int r = 0; r < 4; ++r) {
                int qp = qb + r;
                int ww = (qp >> 4) * 8 + ((qp >> 1) & 7);
                int d2 = (qp & 1) * 256 + d2base;
                Sp[((b2 * 10 + s2 + 1) * 258 + ww + 1) * 512 + d2] =
                    f2h(acc[mi][ni][r]);
            }
        }
    }
}

// ---- output conv (f16), BM=128 BN=64, BK=128 -> Y NCHW fp32 ----
__global__ __launch_bounds__(256) void k_conv_o_mfma(
        const unsigned short* __restrict__ Sp, const unsigned short* __restrict__ Wh,
        const float* __restrict__ bias, float* __restrict__ Y) {
    __shared__ __align__(16) short Ah[16384], Bh[8192];  // [128][128], [64][128]
    const int tid = threadIdx.x;
    const int w = tid >> 6, l = tid & 63;
    const int n   = blockIdx.x >> 4;
    const int yy  = (blockIdx.x >> 1) & 7;
    const int x0  = (blockIdx.x & 1) * 128;
    const int co0 = blockIdx.y * 64;
    const int lm = l & 15, lq = l >> 4;
    const int r4 = l >> 4, c16 = l & 15;                 // pitch-128 stage map

    int arow[8], brow[4];
#pragma unroll
    for (int j = 0; j < 8; ++j) {
        int rt = w * 32 + j * 4 + r4;
        arow[j] = ((n * 10 + yy + 1) * 258 + (x0 + rt + 1)) * 512
                  + ((c16 ^ (rt & 15)) * 8);
    }
#pragma unroll
    for (int j = 0; j < 4; ++j) {
        int rt = w * 16 + j * 4 + r4;
        brow[j] = (co0 + rt) * 4608 + ((c16 ^ (rt & 15)) * 8);
    }
    const int ldsA = w * 8192, ldsB = w * 4096;          // bytes

    int aoff[4][4], boff[2][4];
#pragma unroll
    for (int mi = 0; mi < 4; ++mi) {
        int row = (w & 1) * 64 + mi * 16 + lm;
#pragma unroll
        for (int ks = 0; ks < 4; ++ks)
            aoff[mi][ks] = row * 128 + ((((ks << 2) | lq) ^ (row & 15)) * 8);
    }
#pragma unroll
    for (int ni = 0; ni < 2; ++ni) {
        int row = (w >> 1) * 32 + ni * 16 + lm;
#pragma unroll
        for (int ks = 0; ks < 4; ++ks)
            boff[ni][ks] = row * 128 + ((((ks << 2) | lq) ^ (row & 15)) * 8);
    }

    f32x4 acc[4][2];
#pragma unroll
    for (int ni = 0; ni < 2; ++ni) {
        float b = bias[co0 + (w >> 1) * 32 + ni * 16 + lm];
#pragma unroll
        for (int mi = 0; mi < 4; ++mi) acc[mi][ni] = (f32x4){b, b, b, b};
    }

    for (int tap = 0; tap < 9; ++tap) {
        const int tapoff = ((tap / 3 - 1) * 258 + (tap % 3 - 1)) * 512;
        const int wb = tap * 512;
        for (int ci0 = 0; ci0 < 512; ci0 += 128) {
#pragma unroll
            for (int j = 0; j < 8; ++j)
                gl_lds16(Sp + arow[j] + tapoff + ci0, (char*)Ah + ldsA + j * 1024);
#pragma unroll
            for (int j = 0; j < 4; ++j)
                gl_lds16(Wh + brow[j] + wb + ci0, (char*)Bh + ldsB + j * 1024);
            __syncthreads();
#pragma unroll
            for (int ks = 0; ks < 4; ++ks) {
                half8 a[4], b[2];
#pragma unroll
                for (int mi = 0; mi < 4; ++mi)
                    a[mi] = *(const half8*)&Ah[aoff[mi][ks]];
#pragma unroll
                for (int ni = 0; ni < 2; ++ni)
                    b[ni] = *(const half8*)&Bh[boff[ni][ks]];
#pragma unroll
                for (int mi = 0; mi < 4; ++mi)
#pragma unroll
                    for (int ni = 0; ni < 2; ++ni)
                        acc[mi][ni] = MFMA16F(a[mi], b[ni], acc[mi][ni]);
            }
            __syncthreads();
        }
    }

#pragma unroll
    for (int mi = 0; mi < 4; ++mi) {
        int px = x0 + (w & 1) * 64 + lq * 4 + mi * 16;
#pragma unroll
        for (int ni = 0; ni < 2; ++ni) {
            int co = co0 + (w >> 1) * 32 + ni * 16 + lm;
            *(f32x4*)&Y[n * 1048576 + co * 2048 + yy * 256 + px] = acc[mi][ni];
        }
    }
}

// ---------------------------------------------------------------------------
extern "C" void kernel_launch(void* const* d_in, const int* in_sizes, int n_in,
                              void* d_out, int out_size, void* d_ws, size_t ws_size,
                              hipStream_t stream) {
    const float* q  = (const float*)d_in[0];
    const float* k  = (const float*)d_in[1];
    const float* v  = (const float*)d_in[2];
    const float* Wq = (const float*)d_in[3];
    const float* bq = (const float*)d_in[4];
    const float* Wk = (const float*)d_in[5];
    const float* bk = (const float*)d_in[6];
    const float* Wv = (const float*)d_in[7];
    const float* bv = (const float*)d_in[8];
    const float* Wo = (const float*)d_in[9];
    const float* bo = (const float*)d_in[10];

    // ---- workspace layout (shorts) ----
    unsigned short* W0  = (unsigned short*)d_ws;
    unsigned short* Wqh = W0;                   // 2359296
    unsigned short* Wkh = W0 + 2359296;         // 2359296
    unsigned short* Wvh = W0 + 4718592;         // 2359296
    unsigned short* Xvh = W0 + 7077888;         // 5570560 (ends 12648448)
    unsigned short* Sp  = W0 + 12648448;        // 5283840 (dead r9-Xvl gap;
                                                //  no overlap with Ph@0..8388608,
                                                //  Woh@18219008, Qh/Kh/Vt)
    unsigned short* Woh = W0 + 18219008;        // 2359296 (alive till conv_o)
    unsigned short* Qh  = W0 + 20578304;        // 4194304
    unsigned short* Kh  = W0 + 28966912;        // 4194304
    unsigned short* Vt  = W0 + 33161216;        // 4194304 (alive till pv)
    // reuses: Ph @0 (8388608, over Wqh/Wkh/Wvh/Xvh-head — dead after conv)
    unsigned short* Ph = W0;                    // 8388608 shorts

    // ---- d_out scratch before final writes ----
    float* y_out = (float*)d_out;               // 4194304 floats (written last)
    float* attn  = y_out + 4194304;             // 8388608 floats (by scores_sm)
    unsigned short* Xqh = (unsigned short*)d_out;
    unsigned short* Xkh = (unsigned short*)attn;

    k_prep_fused<<<5600, 256, 0, stream>>>(q, k, v, Wq, Wk, Wv, Wo,
                                           Wqh, Wkh, Wvh, Woh,
                                           Xqh, Xkh, Xvh);
    k_conv_qkv_all<<<dim3(64, 4, 3), 256, 0, stream>>>(
        Xqh, Xkh, Xvh, Wqh, Wkh, Wvh,
        bq, bk, bv, Qh, Kh, Vt);
    k_scores_sm<<<dim3(8, 32), 512, 0, stream>>>(Qh, Kh, attn, Ph, (uint4*)Sp);
    k_pv_mfma<<<dim3(4, 4, 32), 256, 0, stream>>>(Ph, Vt, Sp);
    k_conv_o_mfma<<<dim3(64, 8), 256, 0, stream>>>(Sp, Woh, bo, y_out);
}